// Round 8
// baseline (769.460 us; speedup 1.0000x reference)
//
#include <hip/hip_runtime.h>

typedef __attribute__((ext_vector_type(8))) short short8;
typedef __attribute__((ext_vector_type(4))) float f32x4;

#define MFMA16(a, b, c) __builtin_amdgcn_mfma_f32_16x16x32_bf16(a, b, c, 0, 0, 0)

__device__ __forceinline__ unsigned short f2bf(float x) {
  union { float f; unsigned u; } c; c.f = x;
  unsigned r = c.u + 0x7FFFu + ((c.u >> 16) & 1u);
  return (unsigned short)(r >> 16);
}
__device__ __forceinline__ float bf2f(unsigned short h) {
  union { unsigned u; float f; } c; c.u = ((unsigned)h) << 16; return c.f;
}

// ---------------------------------------------------------------------------
// Workspace (bytes). Same proven layout as r6/r7 (pack regions now half-used:
// hi plane only). Peak < 18.0 MB <= proven-safe 18,087,936.
// ---------------------------------------------------------------------------
static constexpr size_t PK_D1PW = 0;
static constexpr size_t PK_D1W  = 237568;
static constexpr size_t PK_C2W  = 950272;
static constexpr size_t PK_D3PW = 1294336;
static constexpr size_t PK_D3W  = 1409024;
static constexpr size_t PK_C4W  = 1810432;    // ends 2,269,184
static constexpr size_t OFF1_B  = 2269184;    // bf16 [128,18,256]
static constexpr size_t H2P_B   = 2269184;    // f32 [128,96,64] (aliases off1)
static constexpr size_t H1_B    = 5414912;    // f32 [128,96,256]
static constexpr size_t OFF3_B  = 5414912;    // bf16 [128,18,64]
static constexpr size_t H3_B    = 5709824;    // f32 [128,108,64]
static constexpr size_t H4P_B   = 9248768;    // f32 [128,108,16]
static constexpr size_t H5_B    = 10133504;   // f32 [128,128,16]
static constexpr size_t H6P_B   = 11182080;   // f32 [128,512]
static constexpr size_t FCO_B   = 11444224;   // f32 [128,200]

// ---------------------------------------------------------------------------
// Merged weight pre-pack: 6 tensors -> bf16 HI plane only, zero-padded.
// Block ranges: cum {232, 928, 1264, 1376, 1768, 2216}.
// ---------------------------------------------------------------------------
__global__ __launch_bounds__(256) void k_pack6(
    const float* __restrict__ s0, const float* __restrict__ s1,
    const float* __restrict__ s2, const float* __restrict__ s3,
    const float* __restrict__ s4, const float* __restrict__ s5,
    char* __restrict__ ws) {
  int blk = blockIdx.x;
  const float* src; unsigned short* dst; int OC, K, Kp;
  if      (blk <  232) { src=s0; dst=(unsigned short*)(ws+PK_D1PW); OC=18;  K=1800; Kp=1856; }
  else if (blk <  928) { src=s1; dst=(unsigned short*)(ws+PK_D1W);  OC=96;  K=1800; Kp=1856; blk -= 232; }
  else if (blk < 1264) { src=s2; dst=(unsigned short*)(ws+PK_C2W);  OC=96;  K=864;  Kp=896;  blk -= 928; }
  else if (blk < 1376) { src=s3; dst=(unsigned short*)(ws+PK_D3PW); OC=18;  K=864;  Kp=896;  blk -= 1264; }
  else if (blk < 1768) { src=s4; dst=(unsigned short*)(ws+PK_D3W);  OC=108; K=864;  Kp=896;  blk -= 1376; }
  else                 { src=s5; dst=(unsigned short*)(ws+PK_C4W);  OC=108; K=972;  Kp=1024; blk -= 1768; }
  int e = blk * 256 + threadIdx.x;
  int oc = e / Kp, k = e - oc * Kp;
  dst[e] = f2bf((oc < OC && k < K) ? src[(size_t)oc * K + k] : 0.f);
}

// ---------------------------------------------------------------------------
// MFMA implicit-GEMM conv / deform-conv, split-bf16 x2 (AhBh + AlBh).
// r8: bilinear gather uses PAIR-PACKED LDS planes -> 2 x ds_read_b64 per
// sample (was 4 x b32); clamp/pad folded into per-row pair weights.
// B lo plane dropped (weights bf16-hi only).
// OUTMODE: 0 = f32 [b][oc][hw], 1 = bf16 (offset convs), 2 = f32 + maxpool2x2.
// ---------------------------------------------------------------------------
template<bool GATHER, int IC, int OC, int OCPAD, int NT, int H, int W,
         bool HASBIAS, bool HASBN, bool RELU, int OUTMODE, int MINW>
__global__ __launch_bounds__(256, MINW) void k_gemm(
    const float* __restrict__ in,              // [128,IC,H,W] f32
    const unsigned short* __restrict__ offb,   // [128,18,H,W] bf16 (GATHER)
    const unsigned short* __restrict__ wpk,    // packed bf16-hi [OCPAD][KPAD]
    const float* __restrict__ bias,
    const float* __restrict__ bng, const float* __restrict__ bnb,
    const float* __restrict__ bnm, const float* __restrict__ bnv,
    void* __restrict__ outv) {
  constexpr int HW   = H * W;
  constexpr int K    = IC * 9;
  constexpr int NP   = (K + 63) / 64;
  constexpr int KPAD = NP * 64;
  constexpr int TILES = HW / 64;
  constexpr int HP = H + 2, WPD = W + 2;
  constexpr int SAS = 72;                   // u16 per A/B LDS row (64 + pad)
  constexpr int ASZ = 64 * SAS * 2;         // 9216 B
  constexpr int BSZ = OCPAD * SAS * 2;      // hi plane only
  constexpr int SXP = HW + 4;               // pairs per plane (float2 units)
  constexpr int SXS = HW + 8;               // f32 per plane (conv path)
  constexpr int SXSZ = GATHER ? 8 * SXP * 8 : 8 * SXS * 4;
  constexpr int CPT = HW / 32;              // f32 per thread in plane staging
  constexpr int TIDX = GATHER ? 576 * 4  : 0;   // packed pair-bases (u32)
  constexpr int TWT  = GATHER ? 576 * 16 : 0;   // pair weights (float4)
  constexpr int PBST = TIDX + TWT + 2*ASZ + BSZ + 2*SXSZ;
  constexpr int SOUTB = (OUTMODE == 2) ? 64 * (OC + 1) * 4 : 0;
  constexpr int PBYTES = (PBST > SOUTB) ? PBST : SOUTB;
  constexpr int NBV = (OCPAD * 8 + 255) / 256;
  __shared__ __align__(16) char pool[PBYTES];
  unsigned* s_idx = (unsigned*)pool;
  float4*  s_wt  = (float4*)(pool + TIDX);
  unsigned short* s_ah = (unsigned short*)(pool + TIDX + TWT);
  unsigned short* s_al = (unsigned short*)(pool + TIDX + TWT + ASZ);
  unsigned short* s_bh = (unsigned short*)(pool + TIDX + TWT + 2*ASZ);
  float* s_x = (float*)(pool + TIDX + TWT + 2*ASZ + BSZ);
  float* s_out = (float*)pool;              // OUTMODE==2 (aliases, after sync)

  const int tid = threadIdx.x;
  const int b   = blockIdx.x / TILES;
  const int hw0 = (blockIdx.x % TILES) * 64;
  const float* __restrict__ inb = in + (size_t)b * IC * HW;

  if constexpr (GATHER) {
    // bilinear pair-table: exact reference formulas; per-row pair weights
    // fold y-clamp (y1==y0) and zero-padding.
    for (int i = tid; i < 576; i += 256) {
      int px = i / 9, n = i % 9;
      int h = (hw0 + px) / W, w = (hw0 + px) % W;
      float offx = bf2f(offb[(((size_t)b*18 + n)*HW) + h*W + w]);
      float offy = bf2f(offb[(((size_t)b*18 + 9 + n)*HW) + h*W + w]);
      float pxv = (float)(h + n/3) + offx;
      float pyv = (float)(w + n%3) + offy;
      pxv = fminf(fmaxf(pxv, 0.f), (float)(HP - 1));
      pyv = fminf(fmaxf(pyv, 0.f), (float)(WPD - 1));
      float x0 = floorf(pxv), y0 = floorf(pyv);
      float x1 = fminf(x0 + 1.f, (float)(HP - 1));
      float y1 = fminf(y0 + 1.f, (float)(WPD - 1));
      float glt = (1.f + x0 - pxv) * (1.f + y0 - pyv);
      float grb = (1.f - x1 + pxv) * (1.f - y1 + pyv);
      float glb = (1.f + x0 - pxv) * (1.f - y1 + pyv);
      float grt = (1.f - x1 + pxv) * (1.f + y0 - pyv);
      int cx0 = (int)x0, cx1 = (int)x1, cy0 = (int)y0, cy1 = (int)y1;
      unsigned base[2]; float pw[4];
      // row q: corners (cx, cy0) w_a and (cx, cy1) w_b
      int   rcx[2] = {cx0, cx1};
      float rwa[2] = {glt, grt};
      float rwb[2] = {glb, grb};
#pragma unroll
      for (int q = 0; q < 2; ++q) {
        int cx = rcx[q];
        bool rv = (cx >= 1) && (cx <= H);
        bool v0 = rv && (cy0 >= 1) && (cy0 <= W);
        bool v1 = rv && (cy1 >= 1) && (cy1 <= W);
        int a0 = (cx-1)*W + (cy0-1);
        int a1 = (cx-1)*W + (cy1-1);
        float wa = rwa[q], wb = rwb[q];
        if (v0) {
          base[q] = (unsigned)a0;
          pw[2*q]   = wa + ((v1 && a1 == a0) ? wb : 0.f);
          pw[2*q+1] = (v1 && a1 == a0 + 1) ? wb : 0.f;
        } else if (v1) {
          base[q] = (unsigned)a1;
          pw[2*q] = wb; pw[2*q+1] = 0.f;
        } else {
          base[q] = 0u;
          pw[2*q] = 0.f; pw[2*q+1] = 0.f;
        }
      }
      s_idx[i] = base[0] | (base[1] << 16);
      s_wt[i]  = make_float4(pw[0], pw[1], pw[2], pw[3]);
    }
  }

  const int lane = tid & 63;
  const int wv   = tid >> 6;
  const int m16  = lane & 15;
  const int quad = lane >> 4;
  const int px   = tid >> 2;             // A-commit: pixel owned by thread
  const int kb   = (tid & 3) * 16;       // A-commit: 16-k slice
  const int xpl  = tid >> 5;             // plane staging: plane index
  const int xo   = (tid & 31) * CPT;     // plane staging: in-plane offset
  f32x4 acc[NT];
#pragma unroll
  for (int nt = 0; nt < NT; ++nt) acc[nt] = (f32x4){0.f, 0.f, 0.f, 0.f};

  float  rx[2][CPT];
  short8 rb[NBV];

  auto ci0_of = [&](int p) { int c = (p*64)/9; return (c > IC-8) ? IC-8 : c; };

  auto prefX = [&](int p) {
    if (p >= NP) return;
    const float* s = inb + (size_t)(ci0_of(p) + xpl)*HW + xo;
    if constexpr (CPT == 8) {
      float4 a = ((const float4*)s)[0], c = ((const float4*)s)[1];
      rx[p&1][0]=a.x; rx[p&1][1]=a.y; rx[p&1][2]=a.z; rx[p&1][3]=a.w;
      rx[p&1][4]=c.x; rx[p&1][5]=c.y; rx[p&1][6]=c.z; rx[p&1][7]=c.w;
    } else {
      float2 a = ((const float2*)s)[0];
      rx[p&1][0]=a.x; rx[p&1][1]=a.y;
    }
  };
  auto commitX = [&](int p) {
    if (p >= NP) return;
    if constexpr (GATHER) {
      // build overlapping pairs (x[j], x[j+1]); neighbor via wave shuffle
      float* r = rx[p&1];
      float nxt = __shfl_down(r[0], 1);
      if ((tid & 31) == 31) nxt = r[CPT-1];
      float4* d4 = (float4*)((float2*)s_x + (size_t)(p&1)*8*SXP
                             + (size_t)xpl*SXP + xo);
      if constexpr (CPT == 8) {
        d4[0] = make_float4(r[0], r[1], r[1], r[2]);
        d4[1] = make_float4(r[2], r[3], r[3], r[4]);
        d4[2] = make_float4(r[4], r[5], r[5], r[6]);
        d4[3] = make_float4(r[6], r[7], r[7], nxt);
      } else {
        d4[0] = make_float4(r[0], r[1], r[1], nxt);
      }
    } else {
      float* d = s_x + (size_t)(p&1)*8*SXS + xpl*SXS + xo;
      if constexpr (CPT == 8) {
        ((float4*)d)[0] = make_float4(rx[p&1][0],rx[p&1][1],rx[p&1][2],rx[p&1][3]);
        ((float4*)d)[1] = make_float4(rx[p&1][4],rx[p&1][5],rx[p&1][6],rx[p&1][7]);
      } else {
        ((float2*)d)[0] = make_float2(rx[p&1][0],rx[p&1][1]);
      }
    }
  };
  auto prefB = [&](int p) {
    if (p >= NP) return;
    const int k0 = p * 64;
#pragma unroll
    for (int j = 0; j < NBV; ++j) {
      int e = tid + 256*j;
      if (e < OCPAD*8) {
        int oc = e >> 3, kq = e & 7;
        rb[j] = *(const short8*)(wpk + (size_t)oc*KPAD + k0 + kq*8);
      }
    }
  };
  auto commitB = [&]() {
#pragma unroll
    for (int j = 0; j < NBV; ++j) {
      int e = tid + 256*j;
      if (e < OCPAD*8) {
        int oc = e >> 3, kq = e & 7;
        *(short8*)(s_bh + oc*SAS + kq*8) = rb[j];
      }
    }
  };

  prefX(0); prefB(0); commitX(0); prefX(1);
  __syncthreads();

  for (int p = 0; p < NP; ++p) {
    const int k0 = p * 64;
    const int ci0c = ci0_of(p);
    // ---- A commit: gather (pairs) / im2col from LDS, split bf16 hi/lo ----
    float v[16];
    {
      const int kbase = k0 + kb;
      int ci = kbase / 9, n = kbase - ci*9;
      int r = 0, c = 0;
      if constexpr (!GATHER) { int hw = hw0 + px; r = hw / W; c = hw % W; }
#pragma unroll
      for (int i = 0; i < 16; ++i) {
        float val = 0.f;
        if (kbase + i < K) {
          if constexpr (GATHER) {
            unsigned bb = s_idx[px*9 + n];
            float4 w4 = s_wt[px*9 + n];
            const float2* xp = (const float2*)s_x + (size_t)(p&1)*8*SXP
                               + (size_t)(ci - ci0c)*SXP;
            float2 p0 = xp[bb & 0xFFFFu];
            float2 p1 = xp[bb >> 16];
            val = w4.x*p0.x + w4.y*p0.y + w4.z*p1.x + w4.w*p1.y;
          } else {
            const float* xb = s_x + (size_t)(p&1)*8*SXS;
            int rr = r + n/3 - 1, cc = c + n%3 - 1;
            if (rr >= 0 && rr < H && cc >= 0 && cc < W)
              val = xb[(ci - ci0c)*SXS + rr*W + cc];
          }
        }
        v[i] = val;
        if (++n == 9) { n = 0; ++ci; }
      }
    }
    {
      short8 vh0, vh1, vl0, vl1;
#pragma unroll
      for (int i = 0; i < 16; ++i) {
        unsigned short hb = f2bf(v[i]);
        unsigned short lb = f2bf(v[i] - bf2f(hb));
        if (i < 8) { vh0[i] = (short)hb; vl0[i] = (short)lb; }
        else       { vh1[i-8] = (short)hb; vl1[i-8] = (short)lb; }
      }
      *(short8*)&s_ah[px*SAS + kb]     = vh0;
      *(short8*)&s_ah[px*SAS + kb + 8] = vh1;
      *(short8*)&s_al[px*SAS + kb]     = vl0;
      *(short8*)&s_al[px*SAS + kb + 8] = vl1;
    }
    commitB();
    commitX(p + 1);
    prefB(p + 1);
    prefX(p + 2);
    __syncthreads();
#pragma unroll
    for (int ks = 0; ks < 2; ++ks) {
      const int ko = ks*32 + quad*8;
      short8 ah = *(const short8*)&s_ah[(wv*16 + m16)*SAS + ko];
      short8 al = *(const short8*)&s_al[(wv*16 + m16)*SAS + ko];
#pragma unroll
      for (int nt = 0; nt < NT; ++nt) {
        short8 bh = *(const short8*)&s_bh[(nt*16 + m16)*SAS + ko];
        acc[nt] = MFMA16(ah, bh, acc[nt]);
        acc[nt] = MFMA16(al, bh, acc[nt]);
      }
    }
    __syncthreads();
  }

  // epilogue: C row = wv*16 + quad*4 + reg (pixel), col = nt*16 + m16 (oc)
  constexpr int OCS = OC + 1;
#pragma unroll
  for (int nt = 0; nt < NT; ++nt) {
    int oc = nt*16 + m16;
    float bi = 0.f, sc = 1.f, sh = 0.f;
    if (oc < OC) {
      if constexpr (HASBIAS) bi = bias[oc];
      if constexpr (HASBN) {
        sc = bng[oc] * rsqrtf(bnv[oc] + 1e-5f);
        sh = bnb[oc] - bnm[oc] * sc;
      }
    }
#pragma unroll
    for (int reg = 0; reg < 4; ++reg) {
      int rowl = wv*16 + quad*4 + reg;
      float e = (acc[nt][reg] + bi) * sc + sh;
      if constexpr (RELU) e = fmaxf(e, 0.f);
      if (oc < OC) {
        if constexpr (OUTMODE == 0) {
          ((float*)outv)[((size_t)b*OC + oc)*HW + hw0 + rowl] = e;
        } else if constexpr (OUTMODE == 1) {
          ((unsigned short*)outv)[((size_t)b*OC + oc)*HW + hw0 + rowl] = f2bf(e);
        } else {
          s_out[rowl*OCS + oc] = e;
        }
      }
    }
  }
  if constexpr (OUTMODE == 2) {
    __syncthreads();
    constexpr int PR = (64 / W) / 2, PC = W / 2, CNT = PR * PC * OC;
    const int r0 = hw0 / W;
    float* out = (float*)outv;
    for (int e2 = tid; e2 < CNT; e2 += 256) {
      int oc = e2 % OC, q = e2 / OC, pc = q % PC, pr = q / PC;
      int base = ((2*pr)*W + 2*pc)*OCS + oc;
      float a0 = s_out[base],         a1 = s_out[base + OCS];
      float a2 = s_out[base + W*OCS], a3 = s_out[base + W*OCS + OCS];
      float m = fmaxf(fmaxf(a0, a1), fmaxf(a2, a3));
      out[(((size_t)b*OC + oc)*(H/2) + (r0 >> 1) + pr)*(W/2) + pc] = m;
    }
  }
}

// ---------------------------------------------------------------------------
// Small VALU conv (proven): conv5 / conv6 (4x4 spatial).
// ---------------------------------------------------------------------------
template<int IC, int OC, int OCW, int H, int W, bool HASBN, bool RELU, int POOL>
__global__ __launch_bounds__(256) void k_conv(
    const float* __restrict__ in, const float* __restrict__ w,
    const float* __restrict__ bias,
    const float* __restrict__ bng, const float* __restrict__ bnb,
    const float* __restrict__ bnm, const float* __restrict__ bnv,
    float* __restrict__ out) {
  constexpr int HW    = H * W;
  constexpr int TPIX  = (HW < 64) ? HW : 64;
  constexpr int TILES = HW / TPIX;
  constexpr int NGRP  = 256 / TPIX;
  constexpr int OCA   = OCW / NGRP;
  constexpr int RT    = TPIX / W;
  constexpr int WP    = W + 2;
  constexpr int CH    = 4;
  constexpr int RROWS = RT + 2;
  constexpr int SIN   = CH * RROWS * WP;
  __shared__ float s_in[SIN];
  __shared__ __align__(16) float s_w[CH * 9 * OCW];
  const int tid = threadIdx.x;
  const int b   = blockIdx.x / TILES;
  const int r0  = (blockIdx.x % TILES) * RT;
  const int pix = tid % TPIX;
  const int ocg = tid / TPIX;
  const int r = pix / W, c = pix % W;
  float acc[OCA];
#pragma unroll
  for (int o = 0; o < OCA; ++o) acc[o] = 0.f;
  for (int cc = 0; cc < IC; cc += CH) {
    __syncthreads();
    for (int i = tid; i < SIN; i += 256) {
      int ci  = i / (RROWS * WP);
      int rem = i % (RROWS * WP);
      int rr  = rem / WP + r0 - 1;
      int cw  = rem % WP - 1;
      bool ok = (rr >= 0) && (rr < H) && (cw >= 0) && (cw < W);
      s_in[i] = ok ? in[(((size_t)b*IC + cc + ci)*H + rr)*W + cw] : 0.f;
    }
    for (int i = tid; i < CH * 9 * OCW; i += 256) {
      int oc = i % OCW, k = i / OCW;
      s_w[i] = (oc < OC) ? w[((size_t)oc*IC + cc + (k/9))*9 + (k%9)] : 0.f;
    }
    __syncthreads();
#pragma unroll
    for (int ci = 0; ci < CH; ++ci) {
      const float* sp = s_in + ci*RROWS*WP + r*WP + c;
#pragma unroll
      for (int n = 0; n < 9; ++n) {
        float v = sp[(n/3)*WP + (n%3)];
        const float4* w4 = (const float4*)(s_w + (ci*9 + n)*OCW + ocg*OCA);
#pragma unroll
        for (int o = 0; o < OCA/4; ++o) {
          float4 ww = w4[o];
          acc[4*o  ] = fmaf(v, ww.x, acc[4*o  ]);
          acc[4*o+1] = fmaf(v, ww.y, acc[4*o+1]);
          acc[4*o+2] = fmaf(v, ww.z, acc[4*o+2]);
          acc[4*o+3] = fmaf(v, ww.w, acc[4*o+3]);
        }
      }
    }
  }
#pragma unroll
  for (int o = 0; o < OCA; ++o) {
    int oc = ocg*OCA + o;
    float e = 0.f;
    if (oc < OC) {
      e = acc[o] + bias[oc];
      if constexpr (HASBN) {
        float sc = bng[oc] * rsqrtf(bnv[oc] + 1e-5f);
        e = e * sc + (bnb[oc] - bnm[oc]*sc);
      }
      if constexpr (RELU) e = fmaxf(e, 0.f);
    }
    if constexpr (POOL == 0) {
      if (oc < OC)
        out[(((size_t)b*OC + oc)*H + (r0 + r))*W + c] = e;
    } else {
      float e1 = __shfl_xor(e, 1);
      float e2 = __shfl_xor(e, W);
      float e3 = __shfl_xor(e, W + 1);
      float m = (POOL == 1) ? fmaxf(fmaxf(e, e1), fmaxf(e2, e3))
                            : (e + e1 + e2 + e3) * 0.25f;
      if (oc < OC && !(r & 1) && !(c & 1))
        out[(((size_t)b*OC + oc)*(H/2) + (r0 + r)/2)*(W/2) + (c/2)] = m;
    }
  }
}

__global__ __launch_bounds__(128) void k_fc(const float* __restrict__ in,
                                            const float* __restrict__ w,
                                            const float* __restrict__ bias,
                                            float* __restrict__ out) {
  int j = blockIdx.x, b = threadIdx.x;
  const float4* ib = (const float4*)(in + (size_t)b*512);
  const float4* wb = (const float4*)(w + (size_t)j*512);
  float acc = bias[j];
  for (int k = 0; k < 128; ++k) {
    float4 a = ib[k], q = wb[k];
    acc = fmaf(a.x, q.x, fmaf(a.y, q.y, fmaf(a.z, q.z, fmaf(a.w, q.w, acc))));
  }
  out[(size_t)b*200 + j] = acc;
}

__global__ __launch_bounds__(128) void k_fc1(const float* __restrict__ in,
                                             const float* __restrict__ w,
                                             const float* __restrict__ bias,
                                             float* __restrict__ out) {
  int j = blockIdx.x, b = threadIdx.x;
  const float4* ib = (const float4*)(in + (size_t)b*200);
  const float4* wb = (const float4*)(w + (size_t)j*200);
  float acc = bias[j];
  for (int k = 0; k < 50; ++k) {
    float4 a = ib[k], q = wb[k];
    acc = fmaf(a.x, q.x, fmaf(a.y, q.y, fmaf(a.z, q.z, fmaf(a.w, q.w, acc))));
  }
  out[(size_t)b*16 + j] = acc;
}

// ---------------------------------------------------------------------------
extern "C" void kernel_launch(void* const* d_in, const int* in_sizes, int n_in,
                              void* d_out, int out_size, void* d_ws, size_t ws_size,
                              hipStream_t stream) {
  const float* X    = (const float*)d_in[0];
  const float* D1PW = (const float*)d_in[1];
  const float* D1PB = (const float*)d_in[2];
  const float* D1W  = (const float*)d_in[3];
  const float* BN1G = (const float*)d_in[4];
  const float* BN1B = (const float*)d_in[5];
  const float* BN1M = (const float*)d_in[6];
  const float* BN1V = (const float*)d_in[7];
  const float* C2W  = (const float*)d_in[8];
  const float* C2B  = (const float*)d_in[9];
  const float* BN2G = (const float*)d_in[10];
  const float* BN2B = (const float*)d_in[11];
  const float* BN2M = (const float*)d_in[12];
  const float* BN2V = (const float*)d_in[13];
  const float* D3PW = (const float*)d_in[14];
  const float* D3PB = (const float*)d_in[15];
  const float* D3W  = (const float*)d_in[16];
  const float* BN3G = (const float*)d_in[17];
  const float* BN3B = (const float*)d_in[18];
  const float* BN3M = (const float*)d_in[19];
  const float* BN3V = (const float*)d_in[20];
  const float* C4W  = (const float*)d_in[21];
  const float* C4B  = (const float*)d_in[22];
  const float* BN4G = (const float*)d_in[23];
  const float* BN4B = (const float*)d_in[24];
  const float* BN4M = (const float*)d_in[25];
  const float* BN4V = (const float*)d_in[26];
  const float* C5W  = (const float*)d_in[27];
  const float* C5B  = (const float*)d_in[28];
  const float* BN5G = (const float*)d_in[29];
  const float* BN5B = (const float*)d_in[30];
  const float* BN5M = (const float*)d_in[31];
  const float* BN5V = (const float*)d_in[32];
  const float* C6W  = (const float*)d_in[33];
  const float* C6B  = (const float*)d_in[34];
  const float* BN6G = (const float*)d_in[35];
  const float* BN6B = (const float*)d_in[36];
  const float* BN6M = (const float*)d_in[37];
  const float* BN6V = (const float*)d_in[38];
  const float* FCW  = (const float*)d_in[39];
  const float* FCB  = (const float*)d_in[40];
  const float* FC1W = (const float*)d_in[41];
  const float* FC1B = (const float*)d_in[42];

  char* ws = (char*)d_ws;
  unsigned short* pk_d1pw = (unsigned short*)(ws + PK_D1PW);
  unsigned short* pk_d1w  = (unsigned short*)(ws + PK_D1W);
  unsigned short* pk_c2w  = (unsigned short*)(ws + PK_C2W);
  unsigned short* pk_d3pw = (unsigned short*)(ws + PK_D3PW);
  unsigned short* pk_d3w  = (unsigned short*)(ws + PK_D3W);
  unsigned short* pk_c4w  = (unsigned short*)(ws + PK_C4W);
  unsigned short* off1 = (unsigned short*)(ws + OFF1_B);
  unsigned short* off3 = (unsigned short*)(ws + OFF3_B);
  float* h1   = (float*)(ws + H1_B);
  float* h2p  = (float*)(ws + H2P_B);
  float* h3   = (float*)(ws + H3_B);
  float* h4p  = (float*)(ws + H4P_B);
  float* h5   = (float*)(ws + H5_B);
  float* h6p  = (float*)(ws + H6P_B);
  float* fco  = (float*)(ws + FCO_B);
  float* outp = (float*)d_out;

  // merged weight pre-pack (bf16 hi planes, zero-padded)
  k_pack6<<<2216, 256, 0, stream>>>(D1PW, D1W, C2W, D3PW, D3W, C4W, ws);

  // block 1: offset conv -> deform einsum + BN + ReLU
  k_gemm<false,200,18,32,2,16,16,true,false,false,1,3><<<512, 256, 0, stream>>>(
      X, nullptr, pk_d1pw, D1PB, nullptr, nullptr, nullptr, nullptr, off1);
  k_gemm<true,200,96,96,6,16,16,false,true,true,0,2><<<512, 256, 0, stream>>>(
      X, off1, pk_d1w, nullptr, BN1G, BN1B, BN1M, BN1V, h1);
  // block 2: conv + bias + BN + ReLU + maxpool
  k_gemm<false,96,96,96,6,16,16,true,true,true,2,3><<<512, 256, 0, stream>>>(
      h1, nullptr, pk_c2w, C2B, BN2G, BN2B, BN2M, BN2V, h2p);
  // block 3: offset conv -> deform einsum + BN + ReLU
  k_gemm<false,96,18,32,2,8,8,true,false,false,1,3><<<128, 256, 0, stream>>>(
      h2p, nullptr, pk_d3pw, D3PB, nullptr, nullptr, nullptr, nullptr, off3);
  k_gemm<true,96,108,112,7,8,8,false,true,true,0,2><<<128, 256, 0, stream>>>(
      h2p, off3, pk_d3w, nullptr, BN3G, BN3B, BN3M, BN3V, h3);
  // block 4: conv + bias + BN + ReLU + maxpool
  k_gemm<false,108,108,112,7,8,8,true,true,true,2,3><<<128, 256, 0, stream>>>(
      h3, nullptr, pk_c4w, C4B, BN4G, BN4B, BN4M, BN4V, h4p);
  // block 5: conv + BN + ReLU (VALU)
  k_conv<108,128,128,4,4,true,true,0><<<128, 256, 0, stream>>>(
      h4p, C5W, C5B, BN5G, BN5B, BN5M, BN5V, h5);
  // block 6: conv + BN + ReLU + avgpool (VALU, ReLU before avg)
  k_conv<128,128,128,4,4,true,true,2><<<128, 256, 0, stream>>>(
      h5, C6W, C6B, BN6G, BN6B, BN6M, BN6V, h6p);
  // classifier
  k_fc<<<200, 128, 0, stream>>>(h6p, FCW, FCB, fco);
  k_fc1<<<16, 128, 0, stream>>>(fco, FC1W, FC1B, outp);
}

// Round 9
// 717.039 us; speedup vs baseline: 1.0731x; 1.0731x over previous
//
#include <hip/hip_runtime.h>

typedef __attribute__((ext_vector_type(8))) short short8;
typedef __attribute__((ext_vector_type(4))) float f32x4;

#define MFMA16(a, b, c) __builtin_amdgcn_mfma_f32_16x16x32_bf16(a, b, c, 0, 0, 0)

__device__ __forceinline__ unsigned short f2bf(float x) {
  union { float f; unsigned u; } c; c.f = x;
  unsigned r = c.u + 0x7FFFu + ((c.u >> 16) & 1u);
  return (unsigned short)(r >> 16);
}
__device__ __forceinline__ float bf2f(unsigned short h) {
  union { unsigned u; float f; } c; c.u = ((unsigned)h) << 16; return c.f;
}

// ---------------------------------------------------------------------------
// Workspace (bytes). Proven-safe peak (< 18,087,936).
// ---------------------------------------------------------------------------
static constexpr size_t PK_D1PW = 0;          // conv-order 32 x 1856
static constexpr size_t PK_D1W  = 237568;     // GATHER-order 96 x 1920
static constexpr size_t PK_C2W  = 950272;     // conv-order 96 x 896
static constexpr size_t PK_D3PW = 1294336;    // conv-order 32 x 896
static constexpr size_t PK_D3W  = 1409024;    // GATHER-order 112 x 896
static constexpr size_t PK_C4W  = 1810432;    // conv-order 112 x 1024 (ends 2,269,184)
static constexpr size_t OFF1_B  = 2269184;    // bf16 [128,18,256]
static constexpr size_t H2P_B   = 2269184;    // f32 [128,96,64] (aliases off1)
static constexpr size_t H1_B    = 5414912;    // f32 [128,96,256]
static constexpr size_t OFF3_B  = 5414912;    // bf16 [128,18,64]
static constexpr size_t H3_B    = 5709824;    // f32 [128,108,64]
static constexpr size_t H4P_B   = 9248768;    // f32 [128,108,16]
static constexpr size_t H5_B    = 10133504;   // f32 [128,128,16]
static constexpr size_t H6P_B   = 11182080;   // f32 [128,512]
static constexpr size_t FCO_B   = 11444224;   // f32 [128,200]

// ---------------------------------------------------------------------------
// Merged weight pre-pack -> bf16 HI plane. Conv tensors keep k = ci*9+n;
// gather tensors (d1w,d3w) use k' = cb*144 + n*16 + ci_lo (ci = cb*16+ci_lo).
// Block cum ranges: 232, 952, 1288, 1400, 1792, 2240.
// ---------------------------------------------------------------------------
__global__ __launch_bounds__(256) void k_pack6(
    const float* __restrict__ s0, const float* __restrict__ s1,
    const float* __restrict__ s2, const float* __restrict__ s3,
    const float* __restrict__ s4, const float* __restrict__ s5,
    char* __restrict__ ws) {
  int blk = blockIdx.x;
  const float* src; unsigned short* dst; int K, Kp, OC, IC; bool gm;
  if      (blk <  232) { src=s0; dst=(unsigned short*)(ws+PK_D1PW); OC=18;  K=1800; Kp=1856; IC=200; gm=false; }
  else if (blk <  952) { src=s1; dst=(unsigned short*)(ws+PK_D1W);  OC=96;  K=1800; Kp=1920; IC=200; gm=true;  blk -= 232; }
  else if (blk < 1288) { src=s2; dst=(unsigned short*)(ws+PK_C2W);  OC=96;  K=864;  Kp=896;  IC=96;  gm=false; blk -= 952; }
  else if (blk < 1400) { src=s3; dst=(unsigned short*)(ws+PK_D3PW); OC=18;  K=864;  Kp=896;  IC=96;  gm=false; blk -= 1288; }
  else if (blk < 1792) { src=s4; dst=(unsigned short*)(ws+PK_D3W);  OC=108; K=864;  Kp=896;  IC=96;  gm=true;  blk -= 1400; }
  else                 { src=s5; dst=(unsigned short*)(ws+PK_C4W);  OC=108; K=972;  Kp=1024; IC=108; gm=false; blk -= 1792; }
  int e = blk * 256 + threadIdx.x;
  int oc = e / Kp, k = e - oc * Kp;
  float v = 0.f;
  if (oc < OC) {
    if (gm) {
      int NCB = (IC + 15) >> 4;
      if (k < NCB * 144) {
        int cb = k / 144, r = k - cb*144;
        int n = r >> 4, ci = cb*16 + (r & 15);
        if (ci < IC) v = src[(size_t)oc*K + ci*9 + n];
      }
    } else {
      if (k < K) v = src[(size_t)oc*K + k];
    }
  }
  dst[e] = f2bf(v);
}

// ---------------------------------------------------------------------------
// Deform MFMA GEMM (gather), split-bf16 x2 (AhBh + AlBh), k' ordering.
// X staged in LDS as HWC16 chunks [pos][16ci] with 4*pos rotation swizzle:
// gather = 4 corners x 4 ds_read_b128, conflict-free by construction.
// ROLLING: 2-slot chunk window (IC=200); else all chunks resident (IC<=96).
// ---------------------------------------------------------------------------
template<int IC, int OC, int OCPAD, int NT, int H, int W, bool ROLLING>
__global__ __launch_bounds__(256, 2) void k_dgemm(
    const float* __restrict__ in,              // [128,IC,H,W] f32
    const unsigned short* __restrict__ offb,   // [128,18,H,W] bf16
    const unsigned short* __restrict__ wpk,    // packed bf16-hi [OCPAD][KPAD] k'
    const float* __restrict__ bng, const float* __restrict__ bnb,
    const float* __restrict__ bnm, const float* __restrict__ bnv,
    float* __restrict__ out) {                 // [128,OC,H,W] f32
  constexpr int HW   = H * W;
  constexpr int NCB  = (IC + 15) >> 4;
  constexpr int KV   = NCB * 144;
  constexpr int NP   = (KV + 63) / 64;
  constexpr int KPAD = NP * 64;
  constexpr int TILES = HW / 64;
  constexpr int HP = H + 2, WPD = W + 2;
  constexpr int SAS = 72;
  constexpr int ASZ = 64 * SAS * 2;
  constexpr int BSZ = OCPAD * SAS * 2;
  constexpr int CHUNKF = HW * 16;            // floats per chunk
  constexpr int SLOTS  = ROLLING ? 2 : NCB;
  constexpr int XSZ    = SLOTS * CHUNKF * 4;
  constexpr int TIDX = 576 * 4, TWT = 576 * 16;
  constexpr int PBYTES = TIDX + TWT + 2*ASZ + BSZ + XSZ;
  constexpr int NBV = (OCPAD * 8 + 255) / 256;
  __shared__ __align__(16) char pool[PBYTES];
  uchar4* s_idx = (uchar4*)pool;
  float4* s_wt  = (float4*)(pool + TIDX);
  unsigned short* s_ah = (unsigned short*)(pool + TIDX + TWT);
  unsigned short* s_al = (unsigned short*)(pool + TIDX + TWT + ASZ);
  unsigned short* s_bh = (unsigned short*)(pool + TIDX + TWT + 2*ASZ);
  float* s_xt = (float*)(pool + TIDX + TWT + 2*ASZ + BSZ);

  const int tid = threadIdx.x;
  const int b   = blockIdx.x / TILES;
  const int hw0 = (blockIdx.x % TILES) * 64;
  const float* __restrict__ inb = in + (size_t)b * IC * HW;

  // bilinear table (exact reference formulas; zero-pad folded into weights)
  for (int i = tid; i < 576; i += 256) {
    int px2 = i / 9, n = i % 9;
    int h = (hw0 + px2) / W, w = (hw0 + px2) % W;
    float offx = bf2f(offb[(((size_t)b*18 + n)*HW) + h*W + w]);
    float offy = bf2f(offb[(((size_t)b*18 + 9 + n)*HW) + h*W + w]);
    float pxv = (float)(h + n/3) + offx;
    float pyv = (float)(w + n%3) + offy;
    pxv = fminf(fmaxf(pxv, 0.f), (float)(HP - 1));
    pyv = fminf(fmaxf(pyv, 0.f), (float)(WPD - 1));
    float x0 = floorf(pxv), y0 = floorf(pyv);
    float x1 = fminf(x0 + 1.f, (float)(HP - 1));
    float y1 = fminf(y0 + 1.f, (float)(WPD - 1));
    float glt = (1.f + x0 - pxv) * (1.f + y0 - pyv);
    float grb = (1.f - x1 + pxv) * (1.f - y1 + pyv);
    float glb = (1.f + x0 - pxv) * (1.f - y1 + pyv);
    float grt = (1.f - x1 + pxv) * (1.f + y0 - pyv);
    int   cx[4] = {(int)x0, (int)x1, (int)x0, (int)x1};
    int   cy[4] = {(int)y0, (int)y1, (int)y1, (int)y0};
    float gw[4] = {glt, grb, glb, grt};
    unsigned char id[4]; float gg[4];
#pragma unroll
    for (int q = 0; q < 4; ++q) {
      bool ok = (cx[q] >= 1) && (cx[q] <= H) && (cy[q] >= 1) && (cy[q] <= W);
      id[q] = ok ? (unsigned char)((cx[q]-1)*W + (cy[q]-1)) : (unsigned char)0;
      gg[q] = ok ? gw[q] : 0.f;
    }
    s_idx[i] = make_uchar4(id[0], id[1], id[2], id[3]);
    s_wt[i]  = make_float4(gg[0], gg[1], gg[2], gg[3]);
  }

  auto stageX = [&](int cb) {
    const int slot = ROLLING ? (cb & 1) : cb;
    float* dst = s_xt + (size_t)slot * CHUNKF;
    for (int e = tid; e < 16*HW; e += 256) {
      int ci_lo = e / HW, pp = e - ci_lo*HW;
      int ci = cb*16 + ci_lo;
      float v = (ci < IC) ? inb[(size_t)ci*HW + pp] : 0.f;
      dst[pp*16 + ((ci_lo + 4*pp) & 15)] = v;   // 4*pos rotation swizzle
    }
  };
  if (ROLLING) stageX(0);
  else { for (int cb = 0; cb < NCB; ++cb) stageX(cb); }
  int staged = 0;

  const int lane = tid & 63;
  const int wv   = tid >> 6;
  const int m16  = lane & 15;
  const int quad = lane >> 4;
  const int px   = tid >> 2;             // A-commit pixel
  const int kb   = (tid & 3) * 16;       // A-commit 16-k' slice
  f32x4 acc[NT];
#pragma unroll
  for (int nt = 0; nt < NT; ++nt) acc[nt] = (f32x4){0.f, 0.f, 0.f, 0.f};
  short8 rb[NBV];

  auto prefB = [&](int p) {
    if (p >= NP) return;
    const int k0 = p * 64;
#pragma unroll
    for (int j = 0; j < NBV; ++j) {
      int e = tid + 256*j;
      if (e < OCPAD*8) {
        int oc = e >> 3, kq = e & 7;
        rb[j] = *(const short8*)(wpk + (size_t)oc*KPAD + k0 + kq*8);
      }
    }
  };
  auto commitB = [&]() {
#pragma unroll
    for (int j = 0; j < NBV; ++j) {
      int e = tid + 256*j;
      if (e < OCPAD*8) {
        int oc = e >> 3, kq = e & 7;
        *(short8*)(s_bh + oc*SAS + kq*8) = rb[j];
      }
    }
  };

  prefB(0);
  __syncthreads();

  for (int p = 0; p < NP; ++p) {
    // ---- A build: one table entry, 16 conflict-free b128 gather reads ----
    float v[16];
    {
      const int kbase = p*64 + kb;
      if (kbase < KV) {
        const int cb2 = kbase / 144;
        const int rem = kbase - cb2*144;
        const int n   = rem >> 4;
        const int slot = ROLLING ? (cb2 & 1) : cb2;
        const float* xb = s_xt + (size_t)slot * CHUNKF;
        uchar4 t4 = s_idx[px*9 + n];
        float4 w4 = s_wt[px*9 + n];
        float4 A0[4], A1[4], A2[4], A3[4];
        {
          const float* r0 = xb + (int)t4.x * 16;
          const float* r1 = xb + (int)t4.y * 16;
          const float* r2 = xb + (int)t4.z * 16;
          const float* r3 = xb + (int)t4.w * 16;
#pragma unroll
          for (int j = 0; j < 4; ++j) {
            A0[j] = *(const float4*)(r0 + (((j + t4.x) & 3) << 2));
            A1[j] = *(const float4*)(r1 + (((j + t4.y) & 3) << 2));
            A2[j] = *(const float4*)(r2 + (((j + t4.z) & 3) << 2));
            A3[j] = *(const float4*)(r3 + (((j + t4.w) & 3) << 2));
          }
        }
#pragma unroll
        for (int j = 0; j < 4; ++j) {
          v[4*j+0] = w4.x*A0[j].x + w4.y*A1[j].x + w4.z*A2[j].x + w4.w*A3[j].x;
          v[4*j+1] = w4.x*A0[j].y + w4.y*A1[j].y + w4.z*A2[j].y + w4.w*A3[j].y;
          v[4*j+2] = w4.x*A0[j].z + w4.y*A1[j].z + w4.z*A2[j].z + w4.w*A3[j].z;
          v[4*j+3] = w4.x*A0[j].w + w4.y*A1[j].w + w4.z*A2[j].w + w4.w*A3[j].w;
        }
      } else {
#pragma unroll
        for (int i = 0; i < 16; ++i) v[i] = 0.f;
      }
    }
    {
      short8 vh0, vh1, vl0, vl1;
#pragma unroll
      for (int i = 0; i < 16; ++i) {
        unsigned short hb = f2bf(v[i]);
        unsigned short lb = f2bf(v[i] - bf2f(hb));
        if (i < 8) { vh0[i] = (short)hb; vl0[i] = (short)lb; }
        else       { vh1[i-8] = (short)hb; vl1[i-8] = (short)lb; }
      }
      *(short8*)&s_ah[px*SAS + kb]     = vh0;
      *(short8*)&s_ah[px*SAS + kb + 8] = vh1;
      *(short8*)&s_al[px*SAS + kb]     = vl0;
      *(short8*)&s_al[px*SAS + kb + 8] = vl1;
    }
    commitB();
    if (ROLLING) {
      int want = ((p + 1) * 64 + 63) / 144;
      if (want >= NCB) want = NCB - 1;
      if (want > staged) { stageX(want); staged = want; }
    }
    prefB(p + 1);
    __syncthreads();
#pragma unroll
    for (int ks = 0; ks < 2; ++ks) {
      const int ko = ks*32 + quad*8;
      short8 ah = *(const short8*)&s_ah[(wv*16 + m16)*SAS + ko];
      short8 al = *(const short8*)&s_al[(wv*16 + m16)*SAS + ko];
#pragma unroll
      for (int nt = 0; nt < NT; ++nt) {
        short8 bh = *(const short8*)&s_bh[(nt*16 + m16)*SAS + ko];
        acc[nt] = MFMA16(ah, bh, acc[nt]);
        acc[nt] = MFMA16(al, bh, acc[nt]);
      }
    }
    __syncthreads();
  }

  // epilogue: BN + ReLU, f32 out
#pragma unroll
  for (int nt = 0; nt < NT; ++nt) {
    int oc = nt*16 + m16;
    if (oc < OC) {
      float sc = bng[oc] * rsqrtf(bnv[oc] + 1e-5f);
      float sh = bnb[oc] - bnm[oc] * sc;
#pragma unroll
      for (int reg = 0; reg < 4; ++reg) {
        int rowl = wv*16 + quad*4 + reg;
        float e = fmaxf(acc[nt][reg] * sc + sh, 0.f);
        out[((size_t)b*OC + oc)*HW + hw0 + rowl] = e;
      }
    }
  }
}

// ---------------------------------------------------------------------------
// Conv MFMA GEMM (im2col), split-bf16 x2, ci-major k (unchanged r7/r8 path).
// OUTMODE: 1 = bf16 out (offset convs), 2 = f32 + maxpool2x2.
// ---------------------------------------------------------------------------
template<int IC, int OC, int OCPAD, int NT, int H, int W,
         bool HASBIAS, bool HASBN, bool RELU, int OUTMODE, int MINW>
__global__ __launch_bounds__(256, MINW) void k_gemm(
    const float* __restrict__ in,
    const unsigned short* __restrict__ wpk,    // packed bf16-hi [OCPAD][KPAD]
    const float* __restrict__ bias,
    const float* __restrict__ bng, const float* __restrict__ bnb,
    const float* __restrict__ bnm, const float* __restrict__ bnv,
    void* __restrict__ outv) {
  constexpr int HW   = H * W;
  constexpr int K    = IC * 9;
  constexpr int NP   = (K + 63) / 64;
  constexpr int KPAD = NP * 64;
  constexpr int TILES = HW / 64;
  constexpr int SAS = 72;
  constexpr int ASZ = 64 * SAS * 2;
  constexpr int BSZ = OCPAD * SAS * 2;
  constexpr int SXS = HW + 8;
  constexpr int SXSZ = 8 * SXS * 4;
  constexpr int CPT = HW / 32;
  constexpr int PBST = 2*ASZ + BSZ + 2*SXSZ;
  constexpr int SOUTB = (OUTMODE == 2) ? 64 * (OC + 1) * 4 : 0;
  constexpr int PBYTES = (PBST > SOUTB) ? PBST : SOUTB;
  constexpr int NBV = (OCPAD * 8 + 255) / 256;
  __shared__ __align__(16) char pool[PBYTES];
  unsigned short* s_ah = (unsigned short*)pool;
  unsigned short* s_al = (unsigned short*)(pool + ASZ);
  unsigned short* s_bh = (unsigned short*)(pool + 2*ASZ);
  float* s_x  = (float*)(pool + 2*ASZ + BSZ);
  float* s_out = (float*)pool;

  const int tid = threadIdx.x;
  const int b   = blockIdx.x / TILES;
  const int hw0 = (blockIdx.x % TILES) * 64;
  const float* __restrict__ inb = in + (size_t)b * IC * HW;

  const int lane = tid & 63;
  const int wv   = tid >> 6;
  const int m16  = lane & 15;
  const int quad = lane >> 4;
  const int px   = tid >> 2;
  const int kb   = (tid & 3) * 16;
  const int xpl  = tid >> 5;
  const int xo   = (tid & 31) * CPT;
  f32x4 acc[NT];
#pragma unroll
  for (int nt = 0; nt < NT; ++nt) acc[nt] = (f32x4){0.f, 0.f, 0.f, 0.f};

  float  rx[2][CPT];
  short8 rb[NBV];

  auto ci0_of = [&](int p) { int c = (p*64)/9; return (c > IC-8) ? IC-8 : c; };
  auto prefX = [&](int p) {
    if (p >= NP) return;
    const float* s = inb + (size_t)(ci0_of(p) + xpl)*HW + xo;
    if constexpr (CPT == 8) {
      float4 a = ((const float4*)s)[0], c = ((const float4*)s)[1];
      rx[p&1][0]=a.x; rx[p&1][1]=a.y; rx[p&1][2]=a.z; rx[p&1][3]=a.w;
      rx[p&1][4]=c.x; rx[p&1][5]=c.y; rx[p&1][6]=c.z; rx[p&1][7]=c.w;
    } else {
      float2 a = ((const float2*)s)[0];
      rx[p&1][0]=a.x; rx[p&1][1]=a.y;
    }
  };
  auto commitX = [&](int p) {
    if (p >= NP) return;
    float* d = s_x + (size_t)(p&1)*8*SXS + xpl*SXS + xo;
    if constexpr (CPT == 8) {
      ((float4*)d)[0] = make_float4(rx[p&1][0],rx[p&1][1],rx[p&1][2],rx[p&1][3]);
      ((float4*)d)[1] = make_float4(rx[p&1][4],rx[p&1][5],rx[p&1][6],rx[p&1][7]);
    } else {
      ((float2*)d)[0] = make_float2(rx[p&1][0],rx[p&1][1]);
    }
  };
  auto prefB = [&](int p) {
    if (p >= NP) return;
    const int k0 = p * 64;
#pragma unroll
    for (int j = 0; j < NBV; ++j) {
      int e = tid + 256*j;
      if (e < OCPAD*8) {
        int oc = e >> 3, kq = e & 7;
        rb[j] = *(const short8*)(wpk + (size_t)oc*KPAD + k0 + kq*8);
      }
    }
  };
  auto commitB = [&]() {
#pragma unroll
    for (int j = 0; j < NBV; ++j) {
      int e = tid + 256*j;
      if (e < OCPAD*8) {
        int oc = e >> 3, kq = e & 7;
        *(short8*)(s_bh + oc*SAS + kq*8) = rb[j];
      }
    }
  };

  prefX(0); prefB(0); commitX(0); prefX(1);
  __syncthreads();

  for (int p = 0; p < NP; ++p) {
    const int k0 = p * 64;
    const int ci0c = ci0_of(p);
    float v[16];
    {
      const int kbase = k0 + kb;
      int ci = kbase / 9, n = kbase - ci*9;
      int hw = hw0 + px, r = hw / W, c = hw % W;
      const float* xb = s_x + (size_t)(p&1)*8*SXS;
#pragma unroll
      for (int i = 0; i < 16; ++i) {
        float val = 0.f;
        if (kbase + i < K) {
          int rr = r + n/3 - 1, cc = c + n%3 - 1;
          if (rr >= 0 && rr < H && cc >= 0 && cc < W)
            val = xb[(ci - ci0c)*SXS + rr*W + cc];
        }
        v[i] = val;
        if (++n == 9) { n = 0; ++ci; }
      }
    }
    {
      short8 vh0, vh1, vl0, vl1;
#pragma unroll
      for (int i = 0; i < 16; ++i) {
        unsigned short hb = f2bf(v[i]);
        unsigned short lb = f2bf(v[i] - bf2f(hb));
        if (i < 8) { vh0[i] = (short)hb; vl0[i] = (short)lb; }
        else       { vh1[i-8] = (short)hb; vl1[i-8] = (short)lb; }
      }
      *(short8*)&s_ah[px*SAS + kb]     = vh0;
      *(short8*)&s_ah[px*SAS + kb + 8] = vh1;
      *(short8*)&s_al[px*SAS + kb]     = vl0;
      *(short8*)&s_al[px*SAS + kb + 8] = vl1;
    }
    commitB();
    commitX(p + 1);
    prefB(p + 1);
    prefX(p + 2);
    __syncthreads();
#pragma unroll
    for (int ks = 0; ks < 2; ++ks) {
      const int ko = ks*32 + quad*8;
      short8 ah = *(const short8*)&s_ah[(wv*16 + m16)*SAS + ko];
      short8 al = *(const short8*)&s_al[(wv*16 + m16)*SAS + ko];
#pragma unroll
      for (int nt = 0; nt < NT; ++nt) {
        short8 bh = *(const short8*)&s_bh[(nt*16 + m16)*SAS + ko];
        acc[nt] = MFMA16(ah, bh, acc[nt]);
        acc[nt] = MFMA16(al, bh, acc[nt]);
      }
    }
    __syncthreads();
  }

  constexpr int OCS = OC + 1;
#pragma unroll
  for (int nt = 0; nt < NT; ++nt) {
    int oc = nt*16 + m16;
    float bi = 0.f, sc = 1.f, sh = 0.f;
    if (oc < OC) {
      if constexpr (HASBIAS) bi = bias[oc];
      if constexpr (HASBN) {
        sc = bng[oc] * rsqrtf(bnv[oc] + 1e-5f);
        sh = bnb[oc] - bnm[oc] * sc;
      }
    }
#pragma unroll
    for (int reg = 0; reg < 4; ++reg) {
      int rowl = wv*16 + quad*4 + reg;
      float e = (acc[nt][reg] + bi) * sc + sh;
      if constexpr (RELU) e = fmaxf(e, 0.f);
      if (oc < OC) {
        if constexpr (OUTMODE == 1) {
          ((unsigned short*)outv)[((size_t)b*OC + oc)*HW + hw0 + rowl] = f2bf(e);
        } else {
          s_out[rowl*OCS + oc] = e;
        }
      }
    }
  }
  if constexpr (OUTMODE == 2) {
    __syncthreads();
    constexpr int PR = (64 / W) / 2, PC = W / 2, CNT = PR * PC * OC;
    const int r0 = hw0 / W;
    float* out = (float*)outv;
    for (int e2 = tid; e2 < CNT; e2 += 256) {
      int oc = e2 % OC, q = e2 / OC, pc = q % PC, pr = q / PC;
      int base = ((2*pr)*W + 2*pc)*OCS + oc;
      float a0 = s_out[base],         a1 = s_out[base + OCS];
      float a2 = s_out[base + W*OCS], a3 = s_out[base + W*OCS + OCS];
      float m = fmaxf(fmaxf(a0, a1), fmaxf(a2, a3));
      out[(((size_t)b*OC + oc)*(H/2) + (r0 >> 1) + pr)*(W/2) + pc] = m;
    }
  }
}

// ---------------------------------------------------------------------------
// Small VALU conv (proven): conv5 / conv6 (4x4 spatial).
// ---------------------------------------------------------------------------
template<int IC, int OC, int OCW, int H, int W, bool HASBN, bool RELU, int POOL>
__global__ __launch_bounds__(256) void k_conv(
    const float* __restrict__ in, const float* __restrict__ w,
    const float* __restrict__ bias,
    const float* __restrict__ bng, const float* __restrict__ bnb,
    const float* __restrict__ bnm, const float* __restrict__ bnv,
    float* __restrict__ out) {
  constexpr int HW    = H * W;
  constexpr int TPIX  = (HW < 64) ? HW : 64;
  constexpr int TILES = HW / TPIX;
  constexpr int NGRP  = 256 / TPIX;
  constexpr int OCA   = OCW / NGRP;
  constexpr int RT    = TPIX / W;
  constexpr int WP    = W + 2;
  constexpr int CH    = 4;
  constexpr int RROWS = RT + 2;
  constexpr int SIN   = CH * RROWS * WP;
  __shared__ float s_in[SIN];
  __shared__ __align__(16) float s_w[CH * 9 * OCW];
  const int tid = threadIdx.x;
  const int b   = blockIdx.x / TILES;
  const int r0  = (blockIdx.x % TILES) * RT;
  const int pix = tid % TPIX;
  const int ocg = tid / TPIX;
  const int r = pix / W, c = pix % W;
  float acc[OCA];
#pragma unroll
  for (int o = 0; o < OCA; ++o) acc[o] = 0.f;
  for (int cc = 0; cc < IC; cc += CH) {
    __syncthreads();
    for (int i = tid; i < SIN; i += 256) {
      int ci  = i / (RROWS * WP);
      int rem = i % (RROWS * WP);
      int rr  = rem / WP + r0 - 1;
      int cw  = rem % WP - 1;
      bool ok = (rr >= 0) && (rr < H) && (cw >= 0) && (cw < W);
      s_in[i] = ok ? in[(((size_t)b*IC + cc + ci)*H + rr)*W + cw] : 0.f;
    }
    for (int i = tid; i < CH * 9 * OCW; i += 256) {
      int oc = i % OCW, k = i / OCW;
      s_w[i] = (oc < OC) ? w[((size_t)oc*IC + cc + (k/9))*9 + (k%9)] : 0.f;
    }
    __syncthreads();
#pragma unroll
    for (int ci = 0; ci < CH; ++ci) {
      const float* sp = s_in + ci*RROWS*WP + r*WP + c;
#pragma unroll
      for (int n = 0; n < 9; ++n) {
        float v = sp[(n/3)*WP + (n%3)];
        const float4* w4 = (const float4*)(s_w + (ci*9 + n)*OCW + ocg*OCA);
#pragma unroll
        for (int o = 0; o < OCA/4; ++o) {
          float4 ww = w4[o];
          acc[4*o  ] = fmaf(v, ww.x, acc[4*o  ]);
          acc[4*o+1] = fmaf(v, ww.y, acc[4*o+1]);
          acc[4*o+2] = fmaf(v, ww.z, acc[4*o+2]);
          acc[4*o+3] = fmaf(v, ww.w, acc[4*o+3]);
        }
      }
    }
  }
#pragma unroll
  for (int o = 0; o < OCA; ++o) {
    int oc = ocg*OCA + o;
    float e = 0.f;
    if (oc < OC) {
      e = acc[o] + bias[oc];
      if constexpr (HASBN) {
        float sc = bng[oc] * rsqrtf(bnv[oc] + 1e-5f);
        e = e * sc + (bnb[oc] - bnm[oc]*sc);
      }
      if constexpr (RELU) e = fmaxf(e, 0.f);
    }
    if constexpr (POOL == 0) {
      if (oc < OC)
        out[(((size_t)b*OC + oc)*H + (r0 + r))*W + c] = e;
    } else {
      float e1 = __shfl_xor(e, 1);
      float e2 = __shfl_xor(e, W);
      float e3 = __shfl_xor(e, W + 1);
      float m = (POOL == 1) ? fmaxf(fmaxf(e, e1), fmaxf(e2, e3))
                            : (e + e1 + e2 + e3) * 0.25f;
      if (oc < OC && !(r & 1) && !(c & 1))
        out[(((size_t)b*OC + oc)*(H/2) + (r0 + r)/2)*(W/2) + (c/2)] = m;
    }
  }
}

__global__ __launch_bounds__(128) void k_fc(const float* __restrict__ in,
                                            const float* __restrict__ w,
                                            const float* __restrict__ bias,
                                            float* __restrict__ out) {
  int j = blockIdx.x, b = threadIdx.x;
  const float4* ib = (const float4*)(in + (size_t)b*512);
  const float4* wb = (const float4*)(w + (size_t)j*512);
  float acc = bias[j];
  for (int k = 0; k < 128; ++k) {
    float4 a = ib[k], q = wb[k];
    acc = fmaf(a.x, q.x, fmaf(a.y, q.y, fmaf(a.z, q.z, fmaf(a.w, q.w, acc))));
  }
  out[(size_t)b*200 + j] = acc;
}

__global__ __launch_bounds__(128) void k_fc1(const float* __restrict__ in,
                                             const float* __restrict__ w,
                                             const float* __restrict__ bias,
                                             float* __restrict__ out) {
  int j = blockIdx.x, b = threadIdx.x;
  const float4* ib = (const float4*)(in + (size_t)b*200);
  const float4* wb = (const float4*)(w + (size_t)j*200);
  float acc = bias[j];
  for (int k = 0; k < 50; ++k) {
    float4 a = ib[k], q = wb[k];
    acc = fmaf(a.x, q.x, fmaf(a.y, q.y, fmaf(a.z, q.z, fmaf(a.w, q.w, acc))));
  }
  out[(size_t)b*16 + j] = acc;
}

// ---------------------------------------------------------------------------
extern "C" void kernel_launch(void* const* d_in, const int* in_sizes, int n_in,
                              void* d_out, int out_size, void* d_ws, size_t ws_size,
                              hipStream_t stream) {
  const float* X    = (const float*)d_in[0];
  const float* D1PW = (const float*)d_in[1];
  const float* D1PB = (const float*)d_in[2];
  const float* D1W  = (const float*)d_in[3];
  const float* BN1G = (const float*)d_in[4];
  const float* BN1B = (const float*)d_in[5];
  const float* BN1M = (const float*)d_in[6];
  const float* BN1V = (const float*)d_in[7];
  const float* C2W  = (const float*)d_in[8];
  const float* C2B  = (const float*)d_in[9];
  const float* BN2G = (const float*)d_in[10];
  const float* BN2B = (const float*)d_in[11];
  const float* BN2M = (const float*)d_in[12];
  const float* BN2V = (const float*)d_in[13];
  const float* D3PW = (const float*)d_in[14];
  const float* D3PB = (const float*)d_in[15];
  const float* D3W  = (const float*)d_in[16];
  const float* BN3G = (const float*)d_in[17];
  const float* BN3B = (const float*)d_in[18];
  const float* BN3M = (const float*)d_in[19];
  const float* BN3V = (const float*)d_in[20];
  const float* C4W  = (const float*)d_in[21];
  const float* C4B  = (const float*)d_in[22];
  const float* BN4G = (const float*)d_in[23];
  const float* BN4B = (const float*)d_in[24];
  const float* BN4M = (const float*)d_in[25];
  const float* BN4V = (const float*)d_in[26];
  const float* C5W  = (const float*)d_in[27];
  const float* C5B  = (const float*)d_in[28];
  const float* BN5G = (const float*)d_in[29];
  const float* BN5B = (const float*)d_in[30];
  const float* BN5M = (const float*)d_in[31];
  const float* BN5V = (const float*)d_in[32];
  const float* C6W  = (const float*)d_in[33];
  const float* C6B  = (const float*)d_in[34];
  const float* BN6G = (const float*)d_in[35];
  const float* BN6B = (const float*)d_in[36];
  const float* BN6M = (const float*)d_in[37];
  const float* BN6V = (const float*)d_in[38];
  const float* FCW  = (const float*)d_in[39];
  const float* FCB  = (const float*)d_in[40];
  const float* FC1W = (const float*)d_in[41];
  const float* FC1B = (const float*)d_in[42];

  char* ws = (char*)d_ws;
  unsigned short* pk_d1pw = (unsigned short*)(ws + PK_D1PW);
  unsigned short* pk_d1w  = (unsigned short*)(ws + PK_D1W);
  unsigned short* pk_c2w  = (unsigned short*)(ws + PK_C2W);
  unsigned short* pk_d3pw = (unsigned short*)(ws + PK_D3PW);
  unsigned short* pk_d3w  = (unsigned short*)(ws + PK_D3W);
  unsigned short* pk_c4w  = (unsigned short*)(ws + PK_C4W);
  unsigned short* off1 = (unsigned short*)(ws + OFF1_B);
  unsigned short* off3 = (unsigned short*)(ws + OFF3_B);
  float* h1   = (float*)(ws + H1_B);
  float* h2p  = (float*)(ws + H2P_B);
  float* h3   = (float*)(ws + H3_B);
  float* h4p  = (float*)(ws + H4P_B);
  float* h5   = (float*)(ws + H5_B);
  float* h6p  = (float*)(ws + H6P_B);
  float* fco  = (float*)(ws + FCO_B);
  float* outp = (float*)d_out;

  // merged weight pre-pack (bf16 hi planes; gather tensors in k' order)
  k_pack6<<<2240, 256, 0, stream>>>(D1PW, D1W, C2W, D3PW, D3W, C4W, ws);

  // block 1: offset conv -> deform einsum + BN + ReLU
  k_gemm<200,18,32,2,16,16,true,false,false,1,3><<<512, 256, 0, stream>>>(
      X, pk_d1pw, D1PB, nullptr, nullptr, nullptr, nullptr, off1);
  k_dgemm<200,96,96,6,16,16,true><<<512, 256, 0, stream>>>(
      X, off1, pk_d1w, BN1G, BN1B, BN1M, BN1V, h1);
  // block 2: conv + bias + BN + ReLU + maxpool
  k_gemm<96,96,96,6,16,16,true,true,true,2,3><<<512, 256, 0, stream>>>(
      h1, pk_c2w, C2B, BN2G, BN2B, BN2M, BN2V, h2p);
  // block 3: offset conv -> deform einsum + BN + ReLU
  k_gemm<96,18,32,2,8,8,true,false,false,1,3><<<128, 256, 0, stream>>>(
      h2p, pk_d3pw, D3PB, nullptr, nullptr, nullptr, nullptr, off3);
  k_dgemm<96,108,112,7,8,8,false><<<128, 256, 0, stream>>>(
      h2p, off3, pk_d3w, BN3G, BN3B, BN3M, BN3V, h3);
  // block 4: conv + bias + BN + ReLU + maxpool
  k_gemm<108,108,112,7,8,8,true,true,true,2,3><<<128, 256, 0, stream>>>(
      h3, pk_c4w, C4B, BN4G, BN4B, BN4M, BN4V, h4p);
  // block 5: conv + BN + ReLU (VALU)
  k_conv<108,128,128,4,4,true,true,0><<<128, 256, 0, stream>>>(
      h4p, C5W, C5B, BN5G, BN5B, BN5M, BN5V, h5);
  // block 6: conv + BN + ReLU + avgpool (VALU, ReLU before avg)
  k_conv<128,128,128,4,4,true,true,2><<<128, 256, 0, stream>>>(
      h5, C6W, C6B, BN6G, BN6B, BN6M, BN6V, h6p);
  // classifier
  k_fc<<<200, 128, 0, stream>>>(h6p, FCW, FCB, fco);
  k_fc1<<<16, 128, 0, stream>>>(fco, FC1W, FC1B, outp);
}

// Round 10
// 647.325 us; speedup vs baseline: 1.1887x; 1.1077x over previous
//
#include <hip/hip_runtime.h>

typedef __attribute__((ext_vector_type(8))) short short8;
typedef __attribute__((ext_vector_type(4))) float f32x4;

#define MFMA16(a, b, c) __builtin_amdgcn_mfma_f32_16x16x32_bf16(a, b, c, 0, 0, 0)

__device__ __forceinline__ unsigned short f2bf(float x) {
  union { float f; unsigned u; } c; c.f = x;
  unsigned r = c.u + 0x7FFFu + ((c.u >> 16) & 1u);
  return (unsigned short)(r >> 16);
}
__device__ __forceinline__ float bf2f(unsigned short h) {
  union { unsigned u; float f; } c; c.u = ((unsigned)h) << 16; return c.f;
}

// ---------------------------------------------------------------------------
// Workspace (bytes). Proven-safe peak (< 18,087,936).
// ---------------------------------------------------------------------------
static constexpr size_t PK_D1PW = 0;          // conv-order 32 x 1856
static constexpr size_t PK_D1W  = 237568;     // GATHER-order 96 x 1920
static constexpr size_t PK_C2W  = 950272;     // conv-order 96 x 896
static constexpr size_t PK_D3PW = 1294336;    // conv-order 32 x 896
static constexpr size_t PK_D3W  = 1409024;    // GATHER-order 112 x 896
static constexpr size_t PK_C4W  = 1810432;    // conv-order 112 x 1024 (ends 2,269,184)
static constexpr size_t OFF1_B  = 2269184;    // bf16 [128,18,256]
static constexpr size_t H2P_B   = 2269184;    // f32 [128,96,64] (aliases off1)
static constexpr size_t H1_B    = 5414912;    // f32 [128,96,256]
static constexpr size_t OFF3_B  = 5414912;    // bf16 [128,18,64]
static constexpr size_t H3_B    = 5709824;    // f32 [128,108,64]
static constexpr size_t H4P_B   = 9248768;    // f32 [128,108,16]
static constexpr size_t H5_B    = 10133504;   // f32 [128,128,16]
static constexpr size_t H6P_B   = 11182080;   // f32 [128,512]
static constexpr size_t FCO_B   = 11444224;   // f32 [128,200]

// ---------------------------------------------------------------------------
// Merged weight pre-pack -> bf16 HI plane. Conv tensors keep k = ci*9+n;
// gather tensors (d1w,d3w) use k' = cb*144 + n*16 + ci_lo.
// ---------------------------------------------------------------------------
__global__ __launch_bounds__(256) void k_pack6(
    const float* __restrict__ s0, const float* __restrict__ s1,
    const float* __restrict__ s2, const float* __restrict__ s3,
    const float* __restrict__ s4, const float* __restrict__ s5,
    char* __restrict__ ws) {
  int blk = blockIdx.x;
  const float* src; unsigned short* dst; int K, Kp, OC, IC; bool gm;
  if      (blk <  232) { src=s0; dst=(unsigned short*)(ws+PK_D1PW); OC=18;  K=1800; Kp=1856; IC=200; gm=false; }
  else if (blk <  952) { src=s1; dst=(unsigned short*)(ws+PK_D1W);  OC=96;  K=1800; Kp=1920; IC=200; gm=true;  blk -= 232; }
  else if (blk < 1288) { src=s2; dst=(unsigned short*)(ws+PK_C2W);  OC=96;  K=864;  Kp=896;  IC=96;  gm=false; blk -= 952; }
  else if (blk < 1400) { src=s3; dst=(unsigned short*)(ws+PK_D3PW); OC=18;  K=864;  Kp=896;  IC=96;  gm=false; blk -= 1288; }
  else if (blk < 1792) { src=s4; dst=(unsigned short*)(ws+PK_D3W);  OC=108; K=864;  Kp=896;  IC=96;  gm=true;  blk -= 1400; }
  else                 { src=s5; dst=(unsigned short*)(ws+PK_C4W);  OC=108; K=972;  Kp=1024; IC=108; gm=false; blk -= 1792; }
  int e = blk * 256 + threadIdx.x;
  int oc = e / Kp, k = e - oc * Kp;
  float v = 0.f;
  if (oc < OC) {
    if (gm) {
      int NCB = (IC + 15) >> 4;
      if (k < NCB * 144) {
        int cb = k / 144, r = k - cb*144;
        int n = r >> 4, ci = cb*16 + (r & 15);
        if (ci < IC) v = src[(size_t)oc*K + ci*9 + n];
      }
    } else {
      if (k < K) v = src[(size_t)oc*K + k];
    }
  }
  dst[e] = f2bf(v);
}

// ---------------------------------------------------------------------------
// Deform MFMA GEMM (gather), split-bf16 x2 (AhBh + AlBh), k' ordering.
// r10: swizzle rotation is (row>>1)&3 quads (period 8 in row) so that BOTH
// stageX b128 writes (lane = pp) and near-consecutive-row gather b128 reads
// are bank-uniform (r9's (row)&3 rotation had period 4 -> 4-quad clustering).
// ---------------------------------------------------------------------------
template<int IC, int OC, int OCPAD, int NT, int H, int W, bool ROLLING>
__global__ __launch_bounds__(256, 2) void k_dgemm(
    const float* __restrict__ in,              // [128,IC,H,W] f32
    const unsigned short* __restrict__ offb,   // [128,18,H,W] bf16
    const unsigned short* __restrict__ wpk,    // packed bf16-hi [OCPAD][KPAD] k'
    const float* __restrict__ bng, const float* __restrict__ bnb,
    const float* __restrict__ bnm, const float* __restrict__ bnv,
    float* __restrict__ out) {                 // [128,OC,H,W] f32
  constexpr int HW   = H * W;
  constexpr int NCB  = (IC + 15) >> 4;
  constexpr int KV   = NCB * 144;
  constexpr int NP   = (KV + 63) / 64;
  constexpr int KPAD = NP * 64;
  constexpr int TILES = HW / 64;
  constexpr int HP = H + 2, WPD = W + 2;
  constexpr int SAS = 72;
  constexpr int ASZ = 64 * SAS * 2;
  constexpr int BSZ = OCPAD * SAS * 2;
  constexpr int CHUNKF = HW * 16;
  constexpr int SLOTS  = ROLLING ? 2 : NCB;
  constexpr int XSZ    = SLOTS * CHUNKF * 4;
  constexpr int TIDX = 576 * 4, TWT = 576 * 16;
  constexpr int PBYTES = TIDX + TWT + 2*ASZ + BSZ + XSZ;
  constexpr int NBV = (OCPAD * 8 + 255) / 256;
  __shared__ __align__(16) char pool[PBYTES];
  uchar4* s_idx = (uchar4*)pool;
  float4* s_wt  = (float4*)(pool + TIDX);
  unsigned short* s_ah = (unsigned short*)(pool + TIDX + TWT);
  unsigned short* s_al = (unsigned short*)(pool + TIDX + TWT + ASZ);
  unsigned short* s_bh = (unsigned short*)(pool + TIDX + TWT + 2*ASZ);
  float* s_xt = (float*)(pool + TIDX + TWT + 2*ASZ + BSZ);

  const int tid = threadIdx.x;
  const int b   = blockIdx.x / TILES;
  const int hw0 = (blockIdx.x % TILES) * 64;
  const float* __restrict__ inb = in + (size_t)b * IC * HW;

  // bilinear table (exact reference formulas; zero-pad folded into weights)
  for (int i = tid; i < 576; i += 256) {
    int px2 = i / 9, n = i % 9;
    int h = (hw0 + px2) / W, w = (hw0 + px2) % W;
    float offx = bf2f(offb[(((size_t)b*18 + n)*HW) + h*W + w]);
    float offy = bf2f(offb[(((size_t)b*18 + 9 + n)*HW) + h*W + w]);
    float pxv = (float)(h + n/3) + offx;
    float pyv = (float)(w + n%3) + offy;
    pxv = fminf(fmaxf(pxv, 0.f), (float)(HP - 1));
    pyv = fminf(fmaxf(pyv, 0.f), (float)(WPD - 1));
    float x0 = floorf(pxv), y0 = floorf(pyv);
    float x1 = fminf(x0 + 1.f, (float)(HP - 1));
    float y1 = fminf(y0 + 1.f, (float)(WPD - 1));
    float glt = (1.f + x0 - pxv) * (1.f + y0 - pyv);
    float grb = (1.f - x1 + pxv) * (1.f - y1 + pyv);
    float glb = (1.f + x0 - pxv) * (1.f - y1 + pyv);
    float grt = (1.f - x1 + pxv) * (1.f + y0 - pyv);
    int   cx[4] = {(int)x0, (int)x1, (int)x0, (int)x1};
    int   cy[4] = {(int)y0, (int)y1, (int)y1, (int)y0};
    float gw[4] = {glt, grb, glb, grt};
    unsigned char id[4]; float gg[4];
#pragma unroll
    for (int q = 0; q < 4; ++q) {
      bool ok = (cx[q] >= 1) && (cx[q] <= H) && (cy[q] >= 1) && (cy[q] <= W);
      id[q] = ok ? (unsigned char)((cx[q]-1)*W + (cy[q]-1)) : (unsigned char)0;
      gg[q] = ok ? gw[q] : 0.f;
    }
    s_idx[i] = make_uchar4(id[0], id[1], id[2], id[3]);
    s_wt[i]  = make_float4(gg[0], gg[1], gg[2], gg[3]);
  }

  // stage one 16-channel chunk as [pos][16ci], quad-rotated by (pos>>1)&3.
  auto stageX = [&](int cb) {
    const int slot = ROLLING ? (cb & 1) : cb;
    float* dst = s_xt + (size_t)slot * CHUNKF;
    if constexpr (HW == 256) {
      const int pp = tid;
#pragma unroll
      for (int qj = 0; qj < 4; ++qj) {
        float4 v4;
#pragma unroll
        for (int i2 = 0; i2 < 4; ++i2) {
          int ci = cb*16 + qj*4 + i2;
          ((float*)&v4)[i2] = (ci < IC) ? inb[(size_t)ci*HW + pp] : 0.f;
        }
        *(float4*)(dst + pp*16 + ((((pp >> 1) + qj) & 3) << 2)) = v4;
      }
    } else {   // HW == 64
      const int pp = tid & 63;
      const int qj = tid >> 6;
      float4 v4;
#pragma unroll
      for (int i2 = 0; i2 < 4; ++i2) {
        int ci = cb*16 + qj*4 + i2;
        ((float*)&v4)[i2] = (ci < IC) ? inb[(size_t)ci*HW + pp] : 0.f;
      }
      *(float4*)(dst + pp*16 + ((((pp >> 1) + qj) & 3) << 2)) = v4;
    }
  };
  if (ROLLING) stageX(0);
  else { for (int cb = 0; cb < NCB; ++cb) stageX(cb); }
  int staged = 0;

  const int lane = tid & 63;
  const int wv   = tid >> 6;
  const int m16  = lane & 15;
  const int quad = lane >> 4;
  const int px   = tid >> 2;             // A-commit pixel
  const int kb   = (tid & 3) * 16;       // A-commit 16-k' slice
  f32x4 acc[NT];
#pragma unroll
  for (int nt = 0; nt < NT; ++nt) acc[nt] = (f32x4){0.f, 0.f, 0.f, 0.f};
  short8 rb[NBV];

  auto prefB = [&](int p) {
    if (p >= NP) return;
    const int k0 = p * 64;
#pragma unroll
    for (int j = 0; j < NBV; ++j) {
      int e = tid + 256*j;
      if (e < OCPAD*8) {
        int oc = e >> 3, kq = e & 7;
        rb[j] = *(const short8*)(wpk + (size_t)oc*KPAD + k0 + kq*8);
      }
    }
  };
  auto commitB = [&]() {
#pragma unroll
    for (int j = 0; j < NBV; ++j) {
      int e = tid + 256*j;
      if (e < OCPAD*8) {
        int oc = e >> 3, kq = e & 7;
        *(short8*)(s_bh + oc*SAS + kq*8) = rb[j];
      }
    }
  };

  prefB(0);
  __syncthreads();

  for (int p = 0; p < NP; ++p) {
    // ---- A build: 16 bank-uniform b128 gather reads ----
    float v[16];
    {
      const int kbase = p*64 + kb;
      if (kbase < KV) {
        const int cb2 = kbase / 144;
        const int rem = kbase - cb2*144;
        const int n   = rem >> 4;
        const int slot = ROLLING ? (cb2 & 1) : cb2;
        const float* xb = s_xt + (size_t)slot * CHUNKF;
        uchar4 t4 = s_idx[px*9 + n];
        float4 w4 = s_wt[px*9 + n];
        float4 A0[4], A1[4], A2[4], A3[4];
        {
          const int r0i = (int)t4.x, r1i = (int)t4.y;
          const int r2i = (int)t4.z, r3i = (int)t4.w;
          const float* r0 = xb + r0i * 16;
          const float* r1 = xb + r1i * 16;
          const float* r2 = xb + r2i * 16;
          const float* r3 = xb + r3i * 16;
#pragma unroll
          for (int j = 0; j < 4; ++j) {
            A0[j] = *(const float4*)(r0 + ((((r0i >> 1) + j) & 3) << 2));
            A1[j] = *(const float4*)(r1 + ((((r1i >> 1) + j) & 3) << 2));
            A2[j] = *(const float4*)(r2 + ((((r2i >> 1) + j) & 3) << 2));
            A3[j] = *(const float4*)(r3 + ((((r3i >> 1) + j) & 3) << 2));
          }
        }
#pragma unroll
        for (int j = 0; j < 4; ++j) {
          v[4*j+0] = w4.x*A0[j].x + w4.y*A1[j].x + w4.z*A2[j].x + w4.w*A3[j].x;
          v[4*j+1] = w4.x*A0[j].y + w4.y*A1[j].y + w4.z*A2[j].y + w4.w*A3[j].y;
          v[4*j+2] = w4.x*A0[j].z + w4.y*A1[j].z + w4.z*A2[j].z + w4.w*A3[j].z;
          v[4*j+3] = w4.x*A0[j].w + w4.y*A1[j].w + w4.z*A2[j].w + w4.w*A3[j].w;
        }
      } else {
#pragma unroll
        for (int i = 0; i < 16; ++i) v[i] = 0.f;
      }
    }
    {
      short8 vh0, vh1, vl0, vl1;
#pragma unroll
      for (int i = 0; i < 16; ++i) {
        unsigned short hb = f2bf(v[i]);
        unsigned short lb = f2bf(v[i] - bf2f(hb));
        if (i < 8) { vh0[i] = (short)hb; vl0[i] = (short)lb; }
        else       { vh1[i-8] = (short)hb; vl1[i-8] = (short)lb; }
      }
      *(short8*)&s_ah[px*SAS + kb]     = vh0;
      *(short8*)&s_ah[px*SAS + kb + 8] = vh1;
      *(short8*)&s_al[px*SAS + kb]     = vl0;
      *(short8*)&s_al[px*SAS + kb + 8] = vl1;
    }
    commitB();
    if (ROLLING) {
      int want = ((p + 1) * 64 + 63) / 144;
      if (want >= NCB) want = NCB - 1;
      if (want > staged) { stageX(want); staged = want; }
    }
    prefB(p + 1);
    __syncthreads();
#pragma unroll
    for (int ks = 0; ks < 2; ++ks) {
      const int ko = ks*32 + quad*8;
      short8 ah = *(const short8*)&s_ah[(wv*16 + m16)*SAS + ko];
      short8 al = *(const short8*)&s_al[(wv*16 + m16)*SAS + ko];
#pragma unroll
      for (int nt = 0; nt < NT; ++nt) {
        short8 bh = *(const short8*)&s_bh[(nt*16 + m16)*SAS + ko];
        acc[nt] = MFMA16(ah, bh, acc[nt]);
        acc[nt] = MFMA16(al, bh, acc[nt]);
      }
    }
    __syncthreads();
  }

  // epilogue: BN + ReLU, f32 out
#pragma unroll
  for (int nt = 0; nt < NT; ++nt) {
    int oc = nt*16 + m16;
    if (oc < OC) {
      float sc = bng[oc] * rsqrtf(bnv[oc] + 1e-5f);
      float sh = bnb[oc] - bnm[oc] * sc;
#pragma unroll
      for (int reg = 0; reg < 4; ++reg) {
        int rowl = wv*16 + quad*4 + reg;
        float e = fmaxf(acc[nt][reg] * sc + sh, 0.f);
        out[((size_t)b*OC + oc)*HW + hw0 + rowl] = e;
      }
    }
  }
}

// ---------------------------------------------------------------------------
// Conv MFMA GEMM (im2col), ci-major k. ALO: include A-lo plane (split-bf16 x2)
// — offset convs run hi-only (offsets are smooth; bf16 A suffices).
// OUTMODE: 1 = bf16 out (offset convs), 2 = f32 + maxpool2x2.
// ---------------------------------------------------------------------------
template<int IC, int OC, int OCPAD, int NT, int H, int W,
         bool HASBIAS, bool HASBN, bool RELU, int OUTMODE, int MINW, bool ALO>
__global__ __launch_bounds__(256, MINW) void k_gemm(
    const float* __restrict__ in,
    const unsigned short* __restrict__ wpk,    // packed bf16-hi [OCPAD][KPAD]
    const float* __restrict__ bias,
    const float* __restrict__ bng, const float* __restrict__ bnb,
    const float* __restrict__ bnm, const float* __restrict__ bnv,
    void* __restrict__ outv) {
  constexpr int HW   = H * W;
  constexpr int K    = IC * 9;
  constexpr int NP   = (K + 63) / 64;
  constexpr int KPAD = NP * 64;
  constexpr int TILES = HW / 64;
  constexpr int SAS = 72;
  constexpr int ASZ = 64 * SAS * 2;
  constexpr int NA  = ALO ? 2 : 1;
  constexpr int BSZ = OCPAD * SAS * 2;
  constexpr int SXS = HW + 8;
  constexpr int SXSZ = 8 * SXS * 4;
  constexpr int CPT = HW / 32;
  constexpr int PBST = NA*ASZ + BSZ + 2*SXSZ;
  constexpr int SOUTB = (OUTMODE == 2) ? 64 * (OC + 1) * 4 : 0;
  constexpr int PBYTES = (PBST > SOUTB) ? PBST : SOUTB;
  constexpr int NBV = (OCPAD * 8 + 255) / 256;
  __shared__ __align__(16) char pool[PBYTES];
  unsigned short* s_ah = (unsigned short*)pool;
  unsigned short* s_al = (unsigned short*)(pool + ASZ);   // ALO only
  unsigned short* s_bh = (unsigned short*)(pool + NA*ASZ);
  float* s_x  = (float*)(pool + NA*ASZ + BSZ);
  float* s_out = (float*)pool;

  const int tid = threadIdx.x;
  const int b   = blockIdx.x / TILES;
  const int hw0 = (blockIdx.x % TILES) * 64;
  const float* __restrict__ inb = in + (size_t)b * IC * HW;

  const int lane = tid & 63;
  const int wv   = tid >> 6;
  const int m16  = lane & 15;
  const int quad = lane >> 4;
  const int px   = tid >> 2;
  const int kb   = (tid & 3) * 16;
  const int xpl  = tid >> 5;
  const int xo   = (tid & 31) * CPT;
  f32x4 acc[NT];
#pragma unroll
  for (int nt = 0; nt < NT; ++nt) acc[nt] = (f32x4){0.f, 0.f, 0.f, 0.f};

  float  rx[2][CPT];
  short8 rb[NBV];

  auto ci0_of = [&](int p) { int c = (p*64)/9; return (c > IC-8) ? IC-8 : c; };
  auto prefX = [&](int p) {
    if (p >= NP) return;
    const float* s = inb + (size_t)(ci0_of(p) + xpl)*HW + xo;
    if constexpr (CPT == 8) {
      float4 a = ((const float4*)s)[0], c = ((const float4*)s)[1];
      rx[p&1][0]=a.x; rx[p&1][1]=a.y; rx[p&1][2]=a.z; rx[p&1][3]=a.w;
      rx[p&1][4]=c.x; rx[p&1][5]=c.y; rx[p&1][6]=c.z; rx[p&1][7]=c.w;
    } else {
      float2 a = ((const float2*)s)[0];
      rx[p&1][0]=a.x; rx[p&1][1]=a.y;
    }
  };
  auto commitX = [&](int p) {
    if (p >= NP) return;
    float* d = s_x + (size_t)(p&1)*8*SXS + xpl*SXS + xo;
    if constexpr (CPT == 8) {
      ((float4*)d)[0] = make_float4(rx[p&1][0],rx[p&1][1],rx[p&1][2],rx[p&1][3]);
      ((float4*)d)[1] = make_float4(rx[p&1][4],rx[p&1][5],rx[p&1][6],rx[p&1][7]);
    } else {
      ((float2*)d)[0] = make_float2(rx[p&1][0],rx[p&1][1]);
    }
  };
  auto prefB = [&](int p) {
    if (p >= NP) return;
    const int k0 = p * 64;
#pragma unroll
    for (int j = 0; j < NBV; ++j) {
      int e = tid + 256*j;
      if (e < OCPAD*8) {
        int oc = e >> 3, kq = e & 7;
        rb[j] = *(const short8*)(wpk + (size_t)oc*KPAD + k0 + kq*8);
      }
    }
  };
  auto commitB = [&]() {
#pragma unroll
    for (int j = 0; j < NBV; ++j) {
      int e = tid + 256*j;
      if (e < OCPAD*8) {
        int oc = e >> 3, kq = e & 7;
        *(short8*)(s_bh + oc*SAS + kq*8) = rb[j];
      }
    }
  };

  prefX(0); prefB(0); commitX(0); prefX(1);
  __syncthreads();

  for (int p = 0; p < NP; ++p) {
    const int k0 = p * 64;
    const int ci0c = ci0_of(p);
    float v[16];
    {
      const int kbase = k0 + kb;
      int ci = kbase / 9, n = kbase - ci*9;
      int hw = hw0 + px, r = hw / W, c = hw % W;
      const float* xb = s_x + (size_t)(p&1)*8*SXS;
#pragma unroll
      for (int i = 0; i < 16; ++i) {
        float val = 0.f;
        if (kbase + i < K) {
          int rr = r + n/3 - 1, cc = c + n%3 - 1;
          if (rr >= 0 && rr < H && cc >= 0 && cc < W)
            val = xb[(ci - ci0c)*SXS + rr*W + cc];
        }
        v[i] = val;
        if (++n == 9) { n = 0; ++ci; }
      }
    }
    if constexpr (ALO) {
      short8 vh0, vh1, vl0, vl1;
#pragma unroll
      for (int i = 0; i < 16; ++i) {
        unsigned short hb = f2bf(v[i]);
        unsigned short lb = f2bf(v[i] - bf2f(hb));
        if (i < 8) { vh0[i] = (short)hb; vl0[i] = (short)lb; }
        else       { vh1[i-8] = (short)hb; vl1[i-8] = (short)lb; }
      }
      *(short8*)&s_ah[px*SAS + kb]     = vh0;
      *(short8*)&s_ah[px*SAS + kb + 8] = vh1;
      *(short8*)&s_al[px*SAS + kb]     = vl0;
      *(short8*)&s_al[px*SAS + kb + 8] = vl1;
    } else {
      short8 vh0, vh1;
#pragma unroll
      for (int i = 0; i < 16; ++i) {
        unsigned short hb = f2bf(v[i]);
        if (i < 8) vh0[i] = (short)hb; else vh1[i-8] = (short)hb;
      }
      *(short8*)&s_ah[px*SAS + kb]     = vh0;
      *(short8*)&s_ah[px*SAS + kb + 8] = vh1;
    }
    commitB();
    commitX(p + 1);
    prefB(p + 1);
    prefX(p + 2);
    __syncthreads();
#pragma unroll
    for (int ks = 0; ks < 2; ++ks) {
      const int ko = ks*32 + quad*8;
      short8 ah = *(const short8*)&s_ah[(wv*16 + m16)*SAS + ko];
      short8 al;
      if constexpr (ALO) al = *(const short8*)&s_al[(wv*16 + m16)*SAS + ko];
#pragma unroll
      for (int nt = 0; nt < NT; ++nt) {
        short8 bh = *(const short8*)&s_bh[(nt*16 + m16)*SAS + ko];
        acc[nt] = MFMA16(ah, bh, acc[nt]);
        if constexpr (ALO) acc[nt] = MFMA16(al, bh, acc[nt]);
      }
    }
    __syncthreads();
  }

  constexpr int OCS = OC + 1;
#pragma unroll
  for (int nt = 0; nt < NT; ++nt) {
    int oc = nt*16 + m16;
    float bi = 0.f, sc = 1.f, sh = 0.f;
    if (oc < OC) {
      if constexpr (HASBIAS) bi = bias[oc];
      if constexpr (HASBN) {
        sc = bng[oc] * rsqrtf(bnv[oc] + 1e-5f);
        sh = bnb[oc] - bnm[oc] * sc;
      }
    }
#pragma unroll
    for (int reg = 0; reg < 4; ++reg) {
      int rowl = wv*16 + quad*4 + reg;
      float e = (acc[nt][reg] + bi) * sc + sh;
      if constexpr (RELU) e = fmaxf(e, 0.f);
      if (oc < OC) {
        if constexpr (OUTMODE == 1) {
          ((unsigned short*)outv)[((size_t)b*OC + oc)*HW + hw0 + rowl] = f2bf(e);
        } else {
          s_out[rowl*OCS + oc] = e;
        }
      }
    }
  }
  if constexpr (OUTMODE == 2) {
    __syncthreads();
    constexpr int PR = (64 / W) / 2, PC = W / 2, CNT = PR * PC * OC;
    const int r0 = hw0 / W;
    float* out = (float*)outv;
    for (int e2 = tid; e2 < CNT; e2 += 256) {
      int oc = e2 % OC, q = e2 / OC, pc = q % PC, pr = q / PC;
      int base = ((2*pr)*W + 2*pc)*OCS + oc;
      float a0 = s_out[base],         a1 = s_out[base + OCS];
      float a2 = s_out[base + W*OCS], a3 = s_out[base + W*OCS + OCS];
      float m = fmaxf(fmaxf(a0, a1), fmaxf(a2, a3));
      out[(((size_t)b*OC + oc)*(H/2) + (r0 >> 1) + pr)*(W/2) + pc] = m;
    }
  }
}

// ---------------------------------------------------------------------------
// Small VALU conv (proven): conv5 / conv6 (4x4 spatial).
// ---------------------------------------------------------------------------
template<int IC, int OC, int OCW, int H, int W, bool HASBN, bool RELU, int POOL>
__global__ __launch_bounds__(256) void k_conv(
    const float* __restrict__ in, const float* __restrict__ w,
    const float* __restrict__ bias,
    const float* __restrict__ bng, const float* __restrict__ bnb,
    const float* __restrict__ bnm, const float* __restrict__ bnv,
    float* __restrict__ out) {
  constexpr int HW    = H * W;
  constexpr int TPIX  = (HW < 64) ? HW : 64;
  constexpr int TILES = HW / TPIX;
  constexpr int NGRP  = 256 / TPIX;
  constexpr int OCA   = OCW / NGRP;
  constexpr int RT    = TPIX / W;
  constexpr int WP    = W + 2;
  constexpr int CH    = 4;
  constexpr int RROWS = RT + 2;
  constexpr int SIN   = CH * RROWS * WP;
  __shared__ float s_in[SIN];
  __shared__ __align__(16) float s_w[CH * 9 * OCW];
  const int tid = threadIdx.x;
  const int b   = blockIdx.x / TILES;
  const int r0  = (blockIdx.x % TILES) * RT;
  const int pix = tid % TPIX;
  const int ocg = tid / TPIX;
  const int r = pix / W, c = pix % W;
  float acc[OCA];
#pragma unroll
  for (int o = 0; o < OCA; ++o) acc[o] = 0.f;
  for (int cc = 0; cc < IC; cc += CH) {
    __syncthreads();
    for (int i = tid; i < SIN; i += 256) {
      int ci  = i / (RROWS * WP);
      int rem = i % (RROWS * WP);
      int rr  = rem / WP + r0 - 1;
      int cw  = rem % WP - 1;
      bool ok = (rr >= 0) && (rr < H) && (cw >= 0) && (cw < W);
      s_in[i] = ok ? in[(((size_t)b*IC + cc + ci)*H + rr)*W + cw] : 0.f;
    }
    for (int i = tid; i < CH * 9 * OCW; i += 256) {
      int oc = i % OCW, k = i / OCW;
      s_w[i] = (oc < OC) ? w[((size_t)oc*IC + cc + (k/9))*9 + (k%9)] : 0.f;
    }
    __syncthreads();
#pragma unroll
    for (int ci = 0; ci < CH; ++ci) {
      const float* sp = s_in + ci*RROWS*WP + r*WP + c;
#pragma unroll
      for (int n = 0; n < 9; ++n) {
        float v = sp[(n/3)*WP + (n%3)];
        const float4* w4 = (const float4*)(s_w + (ci*9 + n)*OCW + ocg*OCA);
#pragma unroll
        for (int o = 0; o < OCA/4; ++o) {
          float4 ww = w4[o];
          acc[4*o  ] = fmaf(v, ww.x, acc[4*o  ]);
          acc[4*o+1] = fmaf(v, ww.y, acc[4*o+1]);
          acc[4*o+2] = fmaf(v, ww.z, acc[4*o+2]);
          acc[4*o+3] = fmaf(v, ww.w, acc[4*o+3]);
        }
      }
    }
  }
#pragma unroll
  for (int o = 0; o < OCA; ++o) {
    int oc = ocg*OCA + o;
    float e = 0.f;
    if (oc < OC) {
      e = acc[o] + bias[oc];
      if constexpr (HASBN) {
        float sc = bng[oc] * rsqrtf(bnv[oc] + 1e-5f);
        e = e * sc + (bnb[oc] - bnm[oc]*sc);
      }
      if constexpr (RELU) e = fmaxf(e, 0.f);
    }
    if constexpr (POOL == 0) {
      if (oc < OC)
        out[(((size_t)b*OC + oc)*H + (r0 + r))*W + c] = e;
    } else {
      float e1 = __shfl_xor(e, 1);
      float e2 = __shfl_xor(e, W);
      float e3 = __shfl_xor(e, W + 1);
      float m = (POOL == 1) ? fmaxf(fmaxf(e, e1), fmaxf(e2, e3))
                            : (e + e1 + e2 + e3) * 0.25f;
      if (oc < OC && !(r & 1) && !(c & 1))
        out[(((size_t)b*OC + oc)*(H/2) + (r0 + r)/2)*(W/2) + (c/2)] = m;
    }
  }
}

__global__ __launch_bounds__(128) void k_fc(const float* __restrict__ in,
                                            const float* __restrict__ w,
                                            const float* __restrict__ bias,
                                            float* __restrict__ out) {
  int j = blockIdx.x, b = threadIdx.x;
  const float4* ib = (const float4*)(in + (size_t)b*512);
  const float4* wb = (const float4*)(w + (size_t)j*512);
  float acc = bias[j];
  for (int k = 0; k < 128; ++k) {
    float4 a = ib[k], q = wb[k];
    acc = fmaf(a.x, q.x, fmaf(a.y, q.y, fmaf(a.z, q.z, fmaf(a.w, q.w, acc))));
  }
  out[(size_t)b*200 + j] = acc;
}

__global__ __launch_bounds__(128) void k_fc1(const float* __restrict__ in,
                                             const float* __restrict__ w,
                                             const float* __restrict__ bias,
                                             float* __restrict__ out) {
  int j = blockIdx.x, b = threadIdx.x;
  const float4* ib = (const float4*)(in + (size_t)b*200);
  const float4* wb = (const float4*)(w + (size_t)j*200);
  float acc = bias[j];
  for (int k = 0; k < 50; ++k) {
    float4 a = ib[k], q = wb[k];
    acc = fmaf(a.x, q.x, fmaf(a.y, q.y, fmaf(a.z, q.z, fmaf(a.w, q.w, acc))));
  }
  out[(size_t)b*16 + j] = acc;
}

// ---------------------------------------------------------------------------
extern "C" void kernel_launch(void* const* d_in, const int* in_sizes, int n_in,
                              void* d_out, int out_size, void* d_ws, size_t ws_size,
                              hipStream_t stream) {
  const float* X    = (const float*)d_in[0];
  const float* D1PW = (const float*)d_in[1];
  const float* D1PB = (const float*)d_in[2];
  const float* D1W  = (const float*)d_in[3];
  const float* BN1G = (const float*)d_in[4];
  const float* BN1B = (const float*)d_in[5];
  const float* BN1M = (const float*)d_in[6];
  const float* BN1V = (const float*)d_in[7];
  const float* C2W  = (const float*)d_in[8];
  const float* C2B  = (const float*)d_in[9];
  const float* BN2G = (const float*)d_in[10];
  const float* BN2B = (const float*)d_in[11];
  const float* BN2M = (const float*)d_in[12];
  const float* BN2V = (const float*)d_in[13];
  const float* D3PW = (const float*)d_in[14];
  const float* D3PB = (const float*)d_in[15];
  const float* D3W  = (const float*)d_in[16];
  const float* BN3G = (const float*)d_in[17];
  const float* BN3B = (const float*)d_in[18];
  const float* BN3M = (const float*)d_in[19];
  const float* BN3V = (const float*)d_in[20];
  const float* C4W  = (const float*)d_in[21];
  const float* C4B  = (const float*)d_in[22];
  const float* BN4G = (const float*)d_in[23];
  const float* BN4B = (const float*)d_in[24];
  const float* BN4M = (const float*)d_in[25];
  const float* BN4V = (const float*)d_in[26];
  const float* C5W  = (const float*)d_in[27];
  const float* C5B  = (const float*)d_in[28];
  const float* BN5G = (const float*)d_in[29];
  const float* BN5B = (const float*)d_in[30];
  const float* BN5M = (const float*)d_in[31];
  const float* BN5V = (const float*)d_in[32];
  const float* C6W  = (const float*)d_in[33];
  const float* C6B  = (const float*)d_in[34];
  const float* BN6G = (const float*)d_in[35];
  const float* BN6B = (const float*)d_in[36];
  const float* BN6M = (const float*)d_in[37];
  const float* BN6V = (const float*)d_in[38];
  const float* FCW  = (const float*)d_in[39];
  const float* FCB  = (const float*)d_in[40];
  const float* FC1W = (const float*)d_in[41];
  const float* FC1B = (const float*)d_in[42];

  char* ws = (char*)d_ws;
  unsigned short* pk_d1pw = (unsigned short*)(ws + PK_D1PW);
  unsigned short* pk_d1w  = (unsigned short*)(ws + PK_D1W);
  unsigned short* pk_c2w  = (unsigned short*)(ws + PK_C2W);
  unsigned short* pk_d3pw = (unsigned short*)(ws + PK_D3PW);
  unsigned short* pk_d3w  = (unsigned short*)(ws + PK_D3W);
  unsigned short* pk_c4w  = (unsigned short*)(ws + PK_C4W);
  unsigned short* off1 = (unsigned short*)(ws + OFF1_B);
  unsigned short* off3 = (unsigned short*)(ws + OFF3_B);
  float* h1   = (float*)(ws + H1_B);
  float* h2p  = (float*)(ws + H2P_B);
  float* h3   = (float*)(ws + H3_B);
  float* h4p  = (float*)(ws + H4P_B);
  float* h5   = (float*)(ws + H5_B);
  float* h6p  = (float*)(ws + H6P_B);
  float* fco  = (float*)(ws + FCO_B);
  float* outp = (float*)d_out;

  // merged weight pre-pack (bf16 hi planes; gather tensors in k' order)
  k_pack6<<<2240, 256, 0, stream>>>(D1PW, D1W, C2W, D3PW, D3W, C4W, ws);

  // block 1: offset conv (A-hi only) -> deform einsum + BN + ReLU
  k_gemm<200,18,32,2,16,16,true,false,false,1,3,false><<<512, 256, 0, stream>>>(
      X, pk_d1pw, D1PB, nullptr, nullptr, nullptr, nullptr, off1);
  k_dgemm<200,96,96,6,16,16,true><<<512, 256, 0, stream>>>(
      X, off1, pk_d1w, BN1G, BN1B, BN1M, BN1V, h1);
  // block 2: conv + bias + BN + ReLU + maxpool
  k_gemm<96,96,96,6,16,16,true,true,true,2,3,true><<<512, 256, 0, stream>>>(
      h1, pk_c2w, C2B, BN2G, BN2B, BN2M, BN2V, h2p);
  // block 3: offset conv (A-hi only) -> deform einsum + BN + ReLU
  k_gemm<96,18,32,2,8,8,true,false,false,1,3,false><<<128, 256, 0, stream>>>(
      h2p, pk_d3pw, D3PB, nullptr, nullptr, nullptr, nullptr, off3);
  k_dgemm<96,108,112,7,8,8,false><<<128, 256, 0, stream>>>(
      h2p, off3, pk_d3w, BN3G, BN3B, BN3M, BN3V, h3);
  // block 4: conv + bias + BN + ReLU + maxpool
  k_gemm<108,108,112,7,8,8,true,true,true,2,3,true><<<128, 256, 0, stream>>>(
      h3, pk_c4w, C4B, BN4G, BN4B, BN4M, BN4V, h4p);
  // block 5: conv + BN + ReLU (VALU)
  k_conv<108,128,128,4,4,true,true,0><<<128, 256, 0, stream>>>(
      h4p, C5W, C5B, BN5G, BN5B, BN5M, BN5V, h5);
  // block 6: conv + BN + ReLU + avgpool (VALU, ReLU before avg)
  k_conv<128,128,128,4,4,true,true,2><<<128, 256, 0, stream>>>(
      h5, C6W, C6B, BN6G, BN6B, BN6M, BN6V, h6p);
  // classifier
  k_fc<<<200, 128, 0, stream>>>(h6p, FCW, FCB, fco);
  k_fc1<<<16, 128, 0, stream>>>(fco, FC1W, FC1B, outp);
}

// Round 12
// 508.212 us; speedup vs baseline: 1.5141x; 1.2737x over previous
//
#include <hip/hip_runtime.h>

typedef __attribute__((ext_vector_type(8))) short short8;
typedef __attribute__((ext_vector_type(4))) float f32x4;

#define MFMA16(a, b, c) __builtin_amdgcn_mfma_f32_16x16x32_bf16(a, b, c, 0, 0, 0)

__device__ __forceinline__ unsigned short f2bf(float x) {
  union { float f; unsigned u; } c; c.f = x;
  unsigned r = c.u + 0x7FFFu + ((c.u >> 16) & 1u);
  return (unsigned short)(r >> 16);
}
__device__ __forceinline__ float bf2f(unsigned short h) {
  union { unsigned u; float f; } c; c.u = ((unsigned)h) << 16; return c.f;
}

// ---------------------------------------------------------------------------
// Workspace (bytes). Proven-safe peak (< 18,087,936).
// LIVENESS (r12 fix): pt5/pt6 live at [11.55M,12.63M) INSIDE h1's span —
// k_packT must launch AFTER conv2 (h1 dead), not at t0. r11 clobbered them.
// ---------------------------------------------------------------------------
static constexpr size_t PK_D1PW = 0;          // conv-order 32 x 1856
static constexpr size_t PK_D1W  = 237568;     // GATHER-order 96 x 1920
static constexpr size_t PK_C2W  = 950272;     // conv-order 96 x 896
static constexpr size_t PK_D3PW = 1294336;    // conv-order 32 x 896
static constexpr size_t PK_D3W  = 1409024;    // GATHER-order 112 x 896
static constexpr size_t PK_C4W  = 1810432;    // conv-order 112 x 1024 (ends 2,269,184)
static constexpr size_t OFF1_B  = 2269184;    // bf16 [128,18,256]
static constexpr size_t H2P_B   = 2269184;    // f32 [128,96,64] (aliases off1)
static constexpr size_t H1_B    = 5414912;    // f32 [128,96,256] (ends 17,997,824)
static constexpr size_t OFF3_B  = 5414912;    // bf16 [128,18,64]
static constexpr size_t H3_B    = 5709824;    // f32 [128,108,64]
static constexpr size_t H4P_B   = 9248768;    // f32 [128,108,16]
static constexpr size_t H5_B    = 10133504;   // f32 [128,128,16]
static constexpr size_t H6P_B   = 11182080;   // f32 [128,512]
static constexpr size_t FCO_B   = 11444224;   // f32 [128,200] (ends 11,546,624)
static constexpr size_t PT5_B   = 11546624;   // f32 [972][128]   497,664
static constexpr size_t PT6_B   = 12044288;   // f32 [1152][128]  589,824 (ends 12,634,112)

// ---------------------------------------------------------------------------
// Merged weight pre-pack -> bf16 HI plane. Conv tensors keep k = ci*9+n;
// gather tensors (d1w,d3w) use k' = cb*144 + n*16 + ci_lo.
// ---------------------------------------------------------------------------
__global__ __launch_bounds__(256) void k_pack6(
    const float* __restrict__ s0, const float* __restrict__ s1,
    const float* __restrict__ s2, const float* __restrict__ s3,
    const float* __restrict__ s4, const float* __restrict__ s5,
    char* __restrict__ ws) {
  int blk = blockIdx.x;
  const float* src; unsigned short* dst; int K, Kp, OC, IC; bool gm;
  if      (blk <  232) { src=s0; dst=(unsigned short*)(ws+PK_D1PW); OC=18;  K=1800; Kp=1856; IC=200; gm=false; }
  else if (blk <  952) { src=s1; dst=(unsigned short*)(ws+PK_D1W);  OC=96;  K=1800; Kp=1920; IC=200; gm=true;  blk -= 232; }
  else if (blk < 1288) { src=s2; dst=(unsigned short*)(ws+PK_C2W);  OC=96;  K=864;  Kp=896;  IC=96;  gm=false; blk -= 952; }
  else if (blk < 1400) { src=s3; dst=(unsigned short*)(ws+PK_D3PW); OC=18;  K=864;  Kp=896;  IC=96;  gm=false; blk -= 1288; }
  else if (blk < 1792) { src=s4; dst=(unsigned short*)(ws+PK_D3W);  OC=108; K=864;  Kp=896;  IC=96;  gm=true;  blk -= 1400; }
  else                 { src=s5; dst=(unsigned short*)(ws+PK_C4W);  OC=108; K=972;  Kp=1024; IC=108; gm=false; blk -= 1792; }
  int e = blk * 256 + threadIdx.x;
  int oc = e / Kp, k = e - oc * Kp;
  float v = 0.f;
  if (oc < OC) {
    if (gm) {
      int NCB = (IC + 15) >> 4;
      if (k < NCB * 144) {
        int cb = k / 144, r = k - cb*144;
        int n = r >> 4, ci = cb*16 + (r & 15);
        if (ci < IC) v = src[(size_t)oc*K + ci*9 + n];
      }
    } else {
      if (k < K) v = src[(size_t)oc*K + k];
    }
  }
  dst[e] = f2bf(v);
}

// Transpose c5w/c6w to [k][OC] f32 for the tail convs.
// NOTE: must run after conv2 (writes land inside h1's dead region).
__global__ __launch_bounds__(256) void k_packT(
    const float* __restrict__ s5, const float* __restrict__ s6,
    char* __restrict__ ws) {
  int e = blockIdx.x * 256 + threadIdx.x;
  if (e < 124416) {                       // c5: 972 x 128
    int k = e >> 7, oc = e & 127;
    ((float*)(ws + PT5_B))[e] = s5[(size_t)oc*972 + k];
  } else if (e < 124416 + 147456) {       // c6: 1152 x 128
    int e2 = e - 124416;
    int k = e2 >> 7, oc = e2 & 127;
    ((float*)(ws + PT6_B))[e2] = s6[(size_t)oc*1152 + k];
  }
}

// ---------------------------------------------------------------------------
// Deform MFMA GEMM (gather), split-bf16 x2 (AhBh + AlBh), k' ordering.
// Period-8 quad rotation: stageX b128 writes and near-consecutive-row gather
// b128 reads are bank-uniform (r10).
// ---------------------------------------------------------------------------
template<int IC, int OC, int OCPAD, int NT, int H, int W, bool ROLLING>
__global__ __launch_bounds__(256, 2) void k_dgemm(
    const float* __restrict__ in,              // [128,IC,H,W] f32
    const unsigned short* __restrict__ offb,   // [128,18,H,W] bf16
    const unsigned short* __restrict__ wpk,    // packed bf16-hi [OCPAD][KPAD] k'
    const float* __restrict__ bng, const float* __restrict__ bnb,
    const float* __restrict__ bnm, const float* __restrict__ bnv,
    float* __restrict__ out) {                 // [128,OC,H,W] f32
  constexpr int HW   = H * W;
  constexpr int NCB  = (IC + 15) >> 4;
  constexpr int KV   = NCB * 144;
  constexpr int NP   = (KV + 63) / 64;
  constexpr int KPAD = NP * 64;
  constexpr int TILES = HW / 64;
  constexpr int HP = H + 2, WPD = W + 2;
  constexpr int SAS = 72;
  constexpr int ASZ = 64 * SAS * 2;
  constexpr int BSZ = OCPAD * SAS * 2;
  constexpr int CHUNKF = HW * 16;
  constexpr int SLOTS  = ROLLING ? 2 : NCB;
  constexpr int XSZ    = SLOTS * CHUNKF * 4;
  constexpr int TIDX = 576 * 4, TWT = 576 * 16;
  constexpr int PBYTES = TIDX + TWT + 2*ASZ + BSZ + XSZ;
  constexpr int NBV = (OCPAD * 8 + 255) / 256;
  __shared__ __align__(16) char pool[PBYTES];
  uchar4* s_idx = (uchar4*)pool;
  float4* s_wt  = (float4*)(pool + TIDX);
  unsigned short* s_ah = (unsigned short*)(pool + TIDX + TWT);
  unsigned short* s_al = (unsigned short*)(pool + TIDX + TWT + ASZ);
  unsigned short* s_bh = (unsigned short*)(pool + TIDX + TWT + 2*ASZ);
  float* s_xt = (float*)(pool + TIDX + TWT + 2*ASZ + BSZ);

  const int tid = threadIdx.x;
  const int b   = blockIdx.x / TILES;
  const int hw0 = (blockIdx.x % TILES) * 64;
  const float* __restrict__ inb = in + (size_t)b * IC * HW;

  // bilinear table (exact reference formulas; zero-pad folded into weights)
  for (int i = tid; i < 576; i += 256) {
    int px2 = i / 9, n = i % 9;
    int h = (hw0 + px2) / W, w = (hw0 + px2) % W;
    float offx = bf2f(offb[(((size_t)b*18 + n)*HW) + h*W + w]);
    float offy = bf2f(offb[(((size_t)b*18 + 9 + n)*HW) + h*W + w]);
    float pxv = (float)(h + n/3) + offx;
    float pyv = (float)(w + n%3) + offy;
    pxv = fminf(fmaxf(pxv, 0.f), (float)(HP - 1));
    pyv = fminf(fmaxf(pyv, 0.f), (float)(WPD - 1));
    float x0 = floorf(pxv), y0 = floorf(pyv);
    float x1 = fminf(x0 + 1.f, (float)(HP - 1));
    float y1 = fminf(y0 + 1.f, (float)(WPD - 1));
    float glt = (1.f + x0 - pxv) * (1.f + y0 - pyv);
    float grb = (1.f - x1 + pxv) * (1.f - y1 + pyv);
    float glb = (1.f + x0 - pxv) * (1.f - y1 + pyv);
    float grt = (1.f - x1 + pxv) * (1.f + y0 - pyv);
    int   cx[4] = {(int)x0, (int)x1, (int)x0, (int)x1};
    int   cy[4] = {(int)y0, (int)y1, (int)y1, (int)y0};
    float gw[4] = {glt, grb, glb, grt};
    unsigned char id[4]; float gg[4];
#pragma unroll
    for (int q = 0; q < 4; ++q) {
      bool ok = (cx[q] >= 1) && (cx[q] <= H) && (cy[q] >= 1) && (cy[q] <= W);
      id[q] = ok ? (unsigned char)((cx[q]-1)*W + (cy[q]-1)) : (unsigned char)0;
      gg[q] = ok ? gw[q] : 0.f;
    }
    s_idx[i] = make_uchar4(id[0], id[1], id[2], id[3]);
    s_wt[i]  = make_float4(gg[0], gg[1], gg[2], gg[3]);
  }

  // stage one 16-channel chunk as [pos][16ci], quad-rotated by (pos>>1)&3.
  auto stageX = [&](int cb) {
    const int slot = ROLLING ? (cb & 1) : cb;
    float* dst = s_xt + (size_t)slot * CHUNKF;
    if constexpr (HW == 256) {
      const int pp = tid;
#pragma unroll
      for (int qj = 0; qj < 4; ++qj) {
        float4 v4;
#pragma unroll
        for (int i2 = 0; i2 < 4; ++i2) {
          int ci = cb*16 + qj*4 + i2;
          ((float*)&v4)[i2] = (ci < IC) ? inb[(size_t)ci*HW + pp] : 0.f;
        }
        *(float4*)(dst + pp*16 + ((((pp >> 1) + qj) & 3) << 2)) = v4;
      }
    } else {   // HW == 64
      const int pp = tid & 63;
      const int qj = tid >> 6;
      float4 v4;
#pragma unroll
      for (int i2 = 0; i2 < 4; ++i2) {
        int ci = cb*16 + qj*4 + i2;
        ((float*)&v4)[i2] = (ci < IC) ? inb[(size_t)ci*HW + pp] : 0.f;
      }
      *(float4*)(dst + pp*16 + ((((pp >> 1) + qj) & 3) << 2)) = v4;
    }
  };
  if (ROLLING) stageX(0);
  else { for (int cb = 0; cb < NCB; ++cb) stageX(cb); }
  int staged = 0;

  const int lane = tid & 63;
  const int wv   = tid >> 6;
  const int m16  = lane & 15;
  const int quad = lane >> 4;
  const int px   = tid >> 2;             // A-commit pixel
  const int kb   = (tid & 3) * 16;       // A-commit 16-k' slice
  f32x4 acc[NT];
#pragma unroll
  for (int nt = 0; nt < NT; ++nt) acc[nt] = (f32x4){0.f, 0.f, 0.f, 0.f};
  short8 rb[NBV];

  auto prefB = [&](int p) {
    if (p >= NP) return;
    const int k0 = p * 64;
#pragma unroll
    for (int j = 0; j < NBV; ++j) {
      int e = tid + 256*j;
      if (e < OCPAD*8) {
        int oc = e >> 3, kq = e & 7;
        rb[j] = *(const short8*)(wpk + (size_t)oc*KPAD + k0 + kq*8);
      }
    }
  };
  auto commitB = [&]() {
#pragma unroll
    for (int j = 0; j < NBV; ++j) {
      int e = tid + 256*j;
      if (e < OCPAD*8) {
        int oc = e >> 3, kq = e & 7;
        *(short8*)(s_bh + oc*SAS + kq*8) = rb[j];
      }
    }
  };

  prefB(0);
  __syncthreads();

  for (int p = 0; p < NP; ++p) {
    // ---- A build: 16 bank-uniform b128 gather reads ----
    float v[16];
    {
      const int kbase = p*64 + kb;
      if (kbase < KV) {
        const int cb2 = kbase / 144;
        const int rem = kbase - cb2*144;
        const int n   = rem >> 4;
        const int slot = ROLLING ? (cb2 & 1) : cb2;
        const float* xb = s_xt + (size_t)slot * CHUNKF;
        uchar4 t4 = s_idx[px*9 + n];
        float4 w4 = s_wt[px*9 + n];
        float4 A0[4], A1[4], A2[4], A3[4];
        {
          const int r0i = (int)t4.x, r1i = (int)t4.y;
          const int r2i = (int)t4.z, r3i = (int)t4.w;
          const float* r0 = xb + r0i * 16;
          const float* r1 = xb + r1i * 16;
          const float* r2 = xb + r2i * 16;
          const float* r3 = xb + r3i * 16;
#pragma unroll
          for (int j = 0; j < 4; ++j) {
            A0[j] = *(const float4*)(r0 + ((((r0i >> 1) + j) & 3) << 2));
            A1[j] = *(const float4*)(r1 + ((((r1i >> 1) + j) & 3) << 2));
            A2[j] = *(const float4*)(r2 + ((((r2i >> 1) + j) & 3) << 2));
            A3[j] = *(const float4*)(r3 + ((((r3i >> 1) + j) & 3) << 2));
          }
        }
#pragma unroll
        for (int j = 0; j < 4; ++j) {
          v[4*j+0] = w4.x*A0[j].x + w4.y*A1[j].x + w4.z*A2[j].x + w4.w*A3[j].x;
          v[4*j+1] = w4.x*A0[j].y + w4.y*A1[j].y + w4.z*A2[j].y + w4.w*A3[j].y;
          v[4*j+2] = w4.x*A0[j].z + w4.y*A1[j].z + w4.z*A2[j].z + w4.w*A3[j].z;
          v[4*j+3] = w4.x*A0[j].w + w4.y*A1[j].w + w4.z*A2[j].w + w4.w*A3[j].w;
        }
      } else {
#pragma unroll
        for (int i = 0; i < 16; ++i) v[i] = 0.f;
      }
    }
    {
      short8 vh0, vh1, vl0, vl1;
#pragma unroll
      for (int i = 0; i < 16; ++i) {
        unsigned short hb = f2bf(v[i]);
        unsigned short lb = f2bf(v[i] - bf2f(hb));
        if (i < 8) { vh0[i] = (short)hb; vl0[i] = (short)lb; }
        else       { vh1[i-8] = (short)hb; vl1[i-8] = (short)lb; }
      }
      *(short8*)&s_ah[px*SAS + kb]     = vh0;
      *(short8*)&s_ah[px*SAS + kb + 8] = vh1;
      *(short8*)&s_al[px*SAS + kb]     = vl0;
      *(short8*)&s_al[px*SAS + kb + 8] = vl1;
    }
    commitB();
    if (ROLLING) {
      int want = ((p + 1) * 64 + 63) / 144;
      if (want >= NCB) want = NCB - 1;
      if (want > staged) { stageX(want); staged = want; }
    }
    prefB(p + 1);
    __syncthreads();
#pragma unroll
    for (int ks = 0; ks < 2; ++ks) {
      const int ko = ks*32 + quad*8;
      short8 ah = *(const short8*)&s_ah[(wv*16 + m16)*SAS + ko];
      short8 al = *(const short8*)&s_al[(wv*16 + m16)*SAS + ko];
#pragma unroll
      for (int nt = 0; nt < NT; ++nt) {
        short8 bh = *(const short8*)&s_bh[(nt*16 + m16)*SAS + ko];
        acc[nt] = MFMA16(ah, bh, acc[nt]);
        acc[nt] = MFMA16(al, bh, acc[nt]);
      }
    }
    __syncthreads();
  }

  // epilogue: BN + ReLU, f32 out
#pragma unroll
  for (int nt = 0; nt < NT; ++nt) {
    int oc = nt*16 + m16;
    if (oc < OC) {
      float sc = bng[oc] * rsqrtf(bnv[oc] + 1e-5f);
      float sh = bnb[oc] - bnm[oc] * sc;
#pragma unroll
      for (int reg = 0; reg < 4; ++reg) {
        int rowl = wv*16 + quad*4 + reg;
        float e = fmaxf(acc[nt][reg] * sc + sh, 0.f);
        out[((size_t)b*OC + oc)*HW + hw0 + rowl] = e;
      }
    }
  }
}

// ---------------------------------------------------------------------------
// Conv MFMA GEMM (im2col), ci-major k. ALO: include A-lo plane (split-bf16 x2)
// — offset convs run hi-only. OUTMODE: 1 = bf16 out, 2 = f32 + maxpool2x2.
// ---------------------------------------------------------------------------
template<int IC, int OC, int OCPAD, int NT, int H, int W,
         bool HASBIAS, bool HASBN, bool RELU, int OUTMODE, int MINW, bool ALO>
__global__ __launch_bounds__(256, MINW) void k_gemm(
    const float* __restrict__ in,
    const unsigned short* __restrict__ wpk,    // packed bf16-hi [OCPAD][KPAD]
    const float* __restrict__ bias,
    const float* __restrict__ bng, const float* __restrict__ bnb,
    const float* __restrict__ bnm, const float* __restrict__ bnv,
    void* __restrict__ outv) {
  constexpr int HW   = H * W;
  constexpr int K    = IC * 9;
  constexpr int NP   = (K + 63) / 64;
  constexpr int KPAD = NP * 64;
  constexpr int TILES = HW / 64;
  constexpr int SAS = 72;
  constexpr int ASZ = 64 * SAS * 2;
  constexpr int NA  = ALO ? 2 : 1;
  constexpr int BSZ = OCPAD * SAS * 2;
  constexpr int SXS = HW + 8;
  constexpr int SXSZ = 8 * SXS * 4;
  constexpr int CPT = HW / 32;
  constexpr int PBST = NA*ASZ + BSZ + 2*SXSZ;
  constexpr int SOUTB = (OUTMODE == 2) ? 64 * (OC + 1) * 4 : 0;
  constexpr int PBYTES = (PBST > SOUTB) ? PBST : SOUTB;
  constexpr int NBV = (OCPAD * 8 + 255) / 256;
  __shared__ __align__(16) char pool[PBYTES];
  unsigned short* s_ah = (unsigned short*)pool;
  unsigned short* s_al = (unsigned short*)(pool + ASZ);   // ALO only
  unsigned short* s_bh = (unsigned short*)(pool + NA*ASZ);
  float* s_x  = (float*)(pool + NA*ASZ + BSZ);
  float* s_out = (float*)pool;

  const int tid = threadIdx.x;
  const int b   = blockIdx.x / TILES;
  const int hw0 = (blockIdx.x % TILES) * 64;
  const float* __restrict__ inb = in + (size_t)b * IC * HW;

  const int lane = tid & 63;
  const int wv   = tid >> 6;
  const int m16  = lane & 15;
  const int quad = lane >> 4;
  const int px   = tid >> 2;
  const int kb   = (tid & 3) * 16;
  const int xpl  = tid >> 5;
  const int xo   = (tid & 31) * CPT;
  f32x4 acc[NT];
#pragma unroll
  for (int nt = 0; nt < NT; ++nt) acc[nt] = (f32x4){0.f, 0.f, 0.f, 0.f};

  float  rx[2][CPT];
  short8 rb[NBV];

  auto ci0_of = [&](int p) { int c = (p*64)/9; return (c > IC-8) ? IC-8 : c; };
  auto prefX = [&](int p) {
    if (p >= NP) return;
    const float* s = inb + (size_t)(ci0_of(p) + xpl)*HW + xo;
    if constexpr (CPT == 8) {
      float4 a = ((const float4*)s)[0], c = ((const float4*)s)[1];
      rx[p&1][0]=a.x; rx[p&1][1]=a.y; rx[p&1][2]=a.z; rx[p&1][3]=a.w;
      rx[p&1][4]=c.x; rx[p&1][5]=c.y; rx[p&1][6]=c.z; rx[p&1][7]=c.w;
    } else {
      float2 a = ((const float2*)s)[0];
      rx[p&1][0]=a.x; rx[p&1][1]=a.y;
    }
  };
  auto commitX = [&](int p) {
    if (p >= NP) return;
    float* d = s_x + (size_t)(p&1)*8*SXS + xpl*SXS + xo;
    if constexpr (CPT == 8) {
      ((float4*)d)[0] = make_float4(rx[p&1][0],rx[p&1][1],rx[p&1][2],rx[p&1][3]);
      ((float4*)d)[1] = make_float4(rx[p&1][4],rx[p&1][5],rx[p&1][6],rx[p&1][7]);
    } else {
      ((float2*)d)[0] = make_float2(rx[p&1][0],rx[p&1][1]);
    }
  };
  auto prefB = [&](int p) {
    if (p >= NP) return;
    const int k0 = p * 64;
#pragma unroll
    for (int j = 0; j < NBV; ++j) {
      int e = tid + 256*j;
      if (e < OCPAD*8) {
        int oc = e >> 3, kq = e & 7;
        rb[j] = *(const short8*)(wpk + (size_t)oc*KPAD + k0 + kq*8);
      }
    }
  };
  auto commitB = [&]() {
#pragma unroll
    for (int j = 0; j < NBV; ++j) {
      int e = tid + 256*j;
      if (e < OCPAD*8) {
        int oc = e >> 3, kq = e & 7;
        *(short8*)(s_bh + oc*SAS + kq*8) = rb[j];
      }
    }
  };

  prefX(0); prefB(0); commitX(0); prefX(1);
  __syncthreads();

  for (int p = 0; p < NP; ++p) {
    const int k0 = p * 64;
    const int ci0c = ci0_of(p);
    float v[16];
    {
      const int kbase = k0 + kb;
      int ci = kbase / 9, n = kbase - ci*9;
      int hw = hw0 + px, r = hw / W, c = hw % W;
      const float* xb = s_x + (size_t)(p&1)*8*SXS;
#pragma unroll
      for (int i = 0; i < 16; ++i) {
        float val = 0.f;
        if (kbase + i < K) {
          int rr = r + n/3 - 1, cc = c + n%3 - 1;
          if (rr >= 0 && rr < H && cc >= 0 && cc < W)
            val = xb[(ci - ci0c)*SXS + rr*W + cc];
        }
        v[i] = val;
        if (++n == 9) { n = 0; ++ci; }
      }
    }
    if constexpr (ALO) {
      short8 vh0, vh1, vl0, vl1;
#pragma unroll
      for (int i = 0; i < 16; ++i) {
        unsigned short hb = f2bf(v[i]);
        unsigned short lb = f2bf(v[i] - bf2f(hb));
        if (i < 8) { vh0[i] = (short)hb; vl0[i] = (short)lb; }
        else       { vh1[i-8] = (short)hb; vl1[i-8] = (short)lb; }
      }
      *(short8*)&s_ah[px*SAS + kb]     = vh0;
      *(short8*)&s_ah[px*SAS + kb + 8] = vh1;
      *(short8*)&s_al[px*SAS + kb]     = vl0;
      *(short8*)&s_al[px*SAS + kb + 8] = vl1;
    } else {
      short8 vh0, vh1;
#pragma unroll
      for (int i = 0; i < 16; ++i) {
        unsigned short hb = f2bf(v[i]);
        if (i < 8) vh0[i] = (short)hb; else vh1[i-8] = (short)hb;
      }
      *(short8*)&s_ah[px*SAS + kb]     = vh0;
      *(short8*)&s_ah[px*SAS + kb + 8] = vh1;
    }
    commitB();
    commitX(p + 1);
    prefB(p + 1);
    prefX(p + 2);
    __syncthreads();
#pragma unroll
    for (int ks = 0; ks < 2; ++ks) {
      const int ko = ks*32 + quad*8;
      short8 ah = *(const short8*)&s_ah[(wv*16 + m16)*SAS + ko];
      short8 al;
      if constexpr (ALO) al = *(const short8*)&s_al[(wv*16 + m16)*SAS + ko];
#pragma unroll
      for (int nt = 0; nt < NT; ++nt) {
        short8 bh = *(const short8*)&s_bh[(nt*16 + m16)*SAS + ko];
        acc[nt] = MFMA16(ah, bh, acc[nt]);
        if constexpr (ALO) acc[nt] = MFMA16(al, bh, acc[nt]);
      }
    }
    __syncthreads();
  }

  constexpr int OCS = OC + 1;
#pragma unroll
  for (int nt = 0; nt < NT; ++nt) {
    int oc = nt*16 + m16;
    float bi = 0.f, sc = 1.f, sh = 0.f;
    if (oc < OC) {
      if constexpr (HASBIAS) bi = bias[oc];
      if constexpr (HASBN) {
        sc = bng[oc] * rsqrtf(bnv[oc] + 1e-5f);
        sh = bnb[oc] - bnm[oc] * sc;
      }
    }
#pragma unroll
    for (int reg = 0; reg < 4; ++reg) {
      int rowl = wv*16 + quad*4 + reg;
      float e = (acc[nt][reg] + bi) * sc + sh;
      if constexpr (RELU) e = fmaxf(e, 0.f);
      if (oc < OC) {
        if constexpr (OUTMODE == 1) {
          ((unsigned short*)outv)[((size_t)b*OC + oc)*HW + hw0 + rowl] = f2bf(e);
        } else {
          s_out[rowl*OCS + oc] = e;
        }
      }
    }
  }
  if constexpr (OUTMODE == 2) {
    __syncthreads();
    constexpr int PR = (64 / W) / 2, PC = W / 2, CNT = PR * PC * OC;
    const int r0 = hw0 / W;
    float* out = (float*)outv;
    for (int e2 = tid; e2 < CNT; e2 += 256) {
      int oc = e2 % OC, q = e2 / OC, pc = q % PC, pr = q / PC;
      int base = ((2*pr)*W + 2*pc)*OCS + oc;
      float a0 = s_out[base],         a1 = s_out[base + OCS];
      float a2 = s_out[base + W*OCS], a3 = s_out[base + W*OCS + OCS];
      float m = fmaxf(fmaxf(a0, a1), fmaxf(a2, a3));
      out[(((size_t)b*OC + oc)*(H/2) + (r0 >> 1) + pr)*(W/2) + pc] = m;
    }
  }
}

// ---------------------------------------------------------------------------
// Tail conv (4x4 spatial): block = (batch, 32-oc group), ONE barrier.
// Input staged zero-padded 6x6 per channel; weights pre-transposed [k][OC].
// Thread = (oc, 2-pixel row pair). POOLAVG fuses ReLU-then-avgpool via
// __shfl_xor(.,2) (partner pixel-pair is 2 lanes away) -> writes [b][512].
// ---------------------------------------------------------------------------
template<int IC, int OC, bool POOLAVG>
__global__ __launch_bounds__(256, 4) void k_tail(
    const float* __restrict__ in,     // [128, IC, 4, 4]
    const float* __restrict__ wt,     // [IC*9][OC] f32 (transposed)
    const float* __restrict__ bias,
    const float* __restrict__ bng, const float* __restrict__ bnb,
    const float* __restrict__ bnm, const float* __restrict__ bnv,
    float* __restrict__ out) {
  constexpr int NB = OC / 32;
  __shared__ float s_pad[IC * 36];
  const int tid = threadIdx.x;
  const int b = blockIdx.x / NB;
  const int g = blockIdx.x % NB;
  for (int i = tid; i < IC*36; i += 256) {
    int ci = i / 36, pos = i % 36;
    int rr = pos / 6 - 1, cc = pos % 6 - 1;
    bool ok = (rr >= 0) && (rr < 4) && (cc >= 0) && (cc < 4);
    s_pad[i] = ok ? in[((size_t)b*IC + ci)*16 + rr*4 + cc] : 0.f;
  }
  __syncthreads();
  const int oc = g*32 + (tid >> 3);
  const int p  = tid & 7;                 // pixel-pair index
  const int r0 = p >> 1, c0 = (p & 1) * 2;
  float a0 = 0.f, a1 = 0.f;
  const float* wp = wt + oc;
#pragma unroll 2
  for (int ci = 0; ci < IC; ++ci) {
    const float* sp = s_pad + ci*36 + r0*6 + c0;
#pragma unroll
    for (int n = 0; n < 9; ++n) {
      float wv = wp[(size_t)(ci*9 + n)*OC];
      float v0 = sp[(n/3)*6 + (n%3)];
      float v1 = sp[(n/3)*6 + (n%3) + 1];
      a0 = fmaf(wv, v0, a0);
      a1 = fmaf(wv, v1, a1);
    }
  }
  float sc = bng[oc] * rsqrtf(bnv[oc] + 1e-5f);
  float sh = bnb[oc] - bnm[oc]*sc;
  float bi = bias[oc];
  float e0 = fmaxf((a0 + bi)*sc + sh, 0.f);
  float e1 = fmaxf((a1 + bi)*sc + sh, 0.f);
  if constexpr (!POOLAVG) {
    size_t ob = ((size_t)b*OC + oc)*16 + r0*4 + c0;
    out[ob]     = e0;
    out[ob + 1] = e1;
  } else {
    float s = e0 + e1;
    float tot = s + __shfl_xor(s, 2);
    if ((p & 2) == 0) {
      int pr = p >> 2, pc = p & 1;
      out[(size_t)b*512 + oc*4 + pr*2 + pc] = tot * 0.25f;
    }
  }
}

__global__ __launch_bounds__(128) void k_fc(const float* __restrict__ in,
                                            const float* __restrict__ w,
                                            const float* __restrict__ bias,
                                            float* __restrict__ out) {
  int j = blockIdx.x, b = threadIdx.x;
  const float4* ib = (const float4*)(in + (size_t)b*512);
  const float4* wb = (const float4*)(w + (size_t)j*512);
  float acc = bias[j];
  for (int k = 0; k < 128; ++k) {
    float4 a = ib[k], q = wb[k];
    acc = fmaf(a.x, q.x, fmaf(a.y, q.y, fmaf(a.z, q.z, fmaf(a.w, q.w, acc))));
  }
  out[(size_t)b*200 + j] = acc;
}

__global__ __launch_bounds__(128) void k_fc1(const float* __restrict__ in,
                                             const float* __restrict__ w,
                                             const float* __restrict__ bias,
                                             float* __restrict__ out) {
  int j = blockIdx.x, b = threadIdx.x;
  const float4* ib = (const float4*)(in + (size_t)b*200);
  const float4* wb = (const float4*)(w + (size_t)j*200);
  float acc = bias[j];
  for (int k = 0; k < 50; ++k) {
    float4 a = ib[k], q = wb[k];
    acc = fmaf(a.x, q.x, fmaf(a.y, q.y, fmaf(a.z, q.z, fmaf(a.w, q.w, acc))));
  }
  out[(size_t)b*16 + j] = acc;
}

// ---------------------------------------------------------------------------
extern "C" void kernel_launch(void* const* d_in, const int* in_sizes, int n_in,
                              void* d_out, int out_size, void* d_ws, size_t ws_size,
                              hipStream_t stream) {
  const float* X    = (const float*)d_in[0];
  const float* D1PW = (const float*)d_in[1];
  const float* D1PB = (const float*)d_in[2];
  const float* D1W  = (const float*)d_in[3];
  const float* BN1G = (const float*)d_in[4];
  const float* BN1B = (const float*)d_in[5];
  const float* BN1M = (const float*)d_in[6];
  const float* BN1V = (const float*)d_in[7];
  const float* C2W  = (const float*)d_in[8];
  const float* C2B  = (const float*)d_in[9];
  const float* BN2G = (const float*)d_in[10];
  const float* BN2B = (const float*)d_in[11];
  const float* BN2M = (const float*)d_in[12];
  const float* BN2V = (const float*)d_in[13];
  const float* D3PW = (const float*)d_in[14];
  const float* D3PB = (const float*)d_in[15];
  const float* D3W  = (const float*)d_in[16];
  const float* BN3G = (const float*)d_in[17];
  const float* BN3B = (const float*)d_in[18];
  const float* BN3M = (const float*)d_in[19];
  const float* BN3V = (const float*)d_in[20];
  const float* C4W  = (const float*)d_in[21];
  const float* C4B  = (const float*)d_in[22];
  const float* BN4G = (const float*)d_in[23];
  const float* BN4B = (const float*)d_in[24];
  const float* BN4M = (const float*)d_in[25];
  const float* BN4V = (const float*)d_in[26];
  const float* C5W  = (const float*)d_in[27];
  const float* C5B  = (const float*)d_in[28];
  const float* BN5G = (const float*)d_in[29];
  const float* BN5B = (const float*)d_in[30];
  const float* BN5M = (const float*)d_in[31];
  const float* BN5V = (const float*)d_in[32];
  const float* C6W  = (const float*)d_in[33];
  const float* C6B  = (const float*)d_in[34];
  const float* BN6G = (const float*)d_in[35];
  const float* BN6B = (const float*)d_in[36];
  const float* BN6M = (const float*)d_in[37];
  const float* BN6V = (const float*)d_in[38];
  const float* FCW  = (const float*)d_in[39];
  const float* FCB  = (const float*)d_in[40];
  const float* FC1W = (const float*)d_in[41];
  const float* FC1B = (const float*)d_in[42];

  char* ws = (char*)d_ws;
  unsigned short* pk_d1pw = (unsigned short*)(ws + PK_D1PW);
  unsigned short* pk_d1w  = (unsigned short*)(ws + PK_D1W);
  unsigned short* pk_c2w  = (unsigned short*)(ws + PK_C2W);
  unsigned short* pk_d3pw = (unsigned short*)(ws + PK_D3PW);
  unsigned short* pk_d3w  = (unsigned short*)(ws + PK_D3W);
  unsigned short* pk_c4w  = (unsigned short*)(ws + PK_C4W);
  unsigned short* off1 = (unsigned short*)(ws + OFF1_B);
  unsigned short* off3 = (unsigned short*)(ws + OFF3_B);
  float* h1   = (float*)(ws + H1_B);
  float* h2p  = (float*)(ws + H2P_B);
  float* h3   = (float*)(ws + H3_B);
  float* h4p  = (float*)(ws + H4P_B);
  float* h5   = (float*)(ws + H5_B);
  float* h6p  = (float*)(ws + H6P_B);
  float* fco  = (float*)(ws + FCO_B);
  float* pt5  = (float*)(ws + PT5_B);
  float* pt6  = (float*)(ws + PT6_B);
  float* outp = (float*)d_out;

  // weight pre-pack (bf16 hi planes; gather tensors in k' order)
  k_pack6<<<2240, 256, 0, stream>>>(D1PW, D1W, C2W, D3PW, D3W, C4W, ws);

  // block 1: offset conv (A-hi only) -> deform einsum + BN + ReLU
  k_gemm<200,18,32,2,16,16,true,false,false,1,3,false><<<512, 256, 0, stream>>>(
      X, pk_d1pw, D1PB, nullptr, nullptr, nullptr, nullptr, off1);
  k_dgemm<200,96,96,6,16,16,true><<<512, 256, 0, stream>>>(
      X, off1, pk_d1w, BN1G, BN1B, BN1M, BN1V, h1);
  // block 2: conv + bias + BN + ReLU + maxpool
  k_gemm<96,96,96,6,16,16,true,true,true,2,3,true><<<512, 256, 0, stream>>>(
      h1, pk_c2w, C2B, BN2G, BN2B, BN2M, BN2V, h2p);
  // tail-conv weight transpose — h1 now dead; pt5/pt6 live inside its span
  k_packT<<<1062, 256, 0, stream>>>(C5W, C6W, ws);
  // block 3: offset conv (A-hi only) -> deform einsum + BN + ReLU
  k_gemm<96,18,32,2,8,8,true,false,false,1,3,false><<<128, 256, 0, stream>>>(
      h2p, pk_d3pw, D3PB, nullptr, nullptr, nullptr, nullptr, off3);
  k_dgemm<96,108,112,7,8,8,false><<<128, 256, 0, stream>>>(
      h2p, off3, pk_d3w, BN3G, BN3B, BN3M, BN3V, h3);
  // block 4: conv + bias + BN + ReLU + maxpool
  k_gemm<108,108,112,7,8,8,true,true,true,2,3,true><<<128, 256, 0, stream>>>(
      h3, pk_c4w, C4B, BN4G, BN4B, BN4M, BN4V, h4p);
  // block 5: conv + BN + ReLU (tail, 512 blocks)
  k_tail<108,128,false><<<512, 256, 0, stream>>>(
      h4p, pt5, C5B, BN5G, BN5B, BN5M, BN5V, h5);
  // block 6: conv + BN + ReLU + avgpool (tail, fused)
  k_tail<128,128,true><<<512, 256, 0, stream>>>(
      h5, pt6, C6B, BN6G, BN6B, BN6M, BN6V, h6p);
  // classifier
  k_fc<<<200, 128, 0, stream>>>(h6p, FCW, FCB, fco);
  k_fc1<<<16, 128, 0, stream>>>(fco, FC1W, FC1B, outp);
}